// Round 1
// baseline (4107.409 us; speedup 1.0000x reference)
//
#include <hip/hip_runtime.h>
#include <cstddef>
#include <cstdint>

#define B_    256
#define M_    21
#define L_    512
#define P_    16
#define S_    8
#define D_    256
#define T_    63
#define F_    32
#define NT_   16128   // B_*T_
#define HID_  512
#define KC_   336     // M_*P_
#define H_    96
#define LAM_  0.01f

// ---------------------------------------------------------------- utilities
__device__ __forceinline__ float block_sum256(float v, float* red4) {
  #pragma unroll
  for (int off = 32; off > 0; off >>= 1) v += __shfl_down(v, off, 64);
  if ((threadIdx.x & 63) == 0) red4[threadIdx.x >> 6] = v;
  __syncthreads();
  float r = red4[0] + red4[1] + red4[2] + red4[3];
  __syncthreads();
  return r;
}

__device__ __forceinline__ float gelu_exact(float v) {
  return 0.5f * v * (1.0f + erff(v * 0.70710678118654752f));
}

// ---------------------------------------------------------------- norm
__global__ __launch_bounds__(256) void norm_kernel(const float* __restrict__ x,
    float* __restrict__ xn, float* __restrict__ meanb, float* __restrict__ stdb) {
  __shared__ float red[4];
  int bm = blockIdx.x;
  const float* xr = x + (size_t)bm * L_;
  float v0 = xr[threadIdx.x], v1 = xr[threadIdx.x + 256];
  float s = block_sum256(v0 + v1, red);
  float mu = s * (1.0f / L_);
  float d0 = v0 - mu, d1 = v1 - mu;
  float s2 = block_sum256(d0 * d0 + d1 * d1, red);
  float sd = sqrtf(s2 * (1.0f / L_));
  float inv = 1.0f / (sd + 1e-5f);
  float* xo = xn + (size_t)bm * L_;
  xo[threadIdx.x] = d0 * inv;
  xo[threadIdx.x + 256] = d1 * inv;
  if (threadIdx.x == 0) { meanb[bm] = mu; stdb[bm] = sd; }
}

// ---------------------------------------------------------------- im2col
__global__ __launch_bounds__(256) void im2col_kernel(const float* __restrict__ xn,
                                                     float* __restrict__ im) {
  int row = blockIdx.x;            // b*T_ + t
  int b = row / T_, t = row - b * T_;
  const float* xb = xn + (size_t)b * M_ * L_ + t * S_;
  float* o = im + (size_t)row * KC_;
  for (int i = threadIdx.x; i < KC_; i += 256) {
    int m = i >> 4, p = i & 15;
    o[i] = xb[m * L_ + p];
  }
}

// ---------------------------------------------------------------- pos-enc + dup
__global__ __launch_bounds__(256) void add_pe_kernel(const float* __restrict__ g,
    float* __restrict__ tb, float* __restrict__ sb) {
  int row = blockIdx.x;
  int d = threadIdx.x;
  int t = row % T_;
  size_t idx = (size_t)row * D_ + d;
  float freq = expf((float)(d & ~1) * (-9.210340371976184f / 256.0f));
  float ang = (float)t * freq;
  float pe = (d & 1) ? cosf(ang) : sinf(ang);
  float h = g[idx] + pe;
  tb[idx] = h;
  sb[idx] = h;
}

// ---------------------------------------------------------------- generic GEMM: C = A @ W^T + bias
// A: (N,K), W: (Dout,K), C: (N,Dout). K multiple of 16, rows of A/W 16B-aligned.
template <int ACT>
__global__ __launch_bounds__(256) void gemm_bias(const float* __restrict__ A,
    const float* __restrict__ W, const float* __restrict__ bias, float* __restrict__ C,
    int N, int K, int Dout) {
  __shared__ float As[16][64];
  __shared__ float Bs[16][64];
  const int tid = threadIdx.x;
  const int row0 = blockIdx.y * 64;
  const int col0 = blockIdx.x * 64;
  const int lr = tid >> 2;          // 0..63
  const int lk = (tid & 3) << 2;    // 0,4,8,12
  const int tx = tid & 15, ty = tid >> 4;
  float acc[4][4] = {{0.f}};
  for (int k0 = 0; k0 < K; k0 += 16) {
    float4 av = make_float4(0.f, 0.f, 0.f, 0.f);
    float4 wv = make_float4(0.f, 0.f, 0.f, 0.f);
    int arow = row0 + lr;
    if (arow < N) av = *reinterpret_cast<const float4*>(A + (size_t)arow * K + k0 + lk);
    int wrow = col0 + lr;
    if (wrow < Dout) wv = *reinterpret_cast<const float4*>(W + (size_t)wrow * K + k0 + lk);
    As[lk + 0][lr] = av.x; As[lk + 1][lr] = av.y; As[lk + 2][lr] = av.z; As[lk + 3][lr] = av.w;
    Bs[lk + 0][lr] = wv.x; Bs[lk + 1][lr] = wv.y; Bs[lk + 2][lr] = wv.z; Bs[lk + 3][lr] = wv.w;
    __syncthreads();
    #pragma unroll
    for (int kk = 0; kk < 16; ++kk) {
      float a4[4], b4[4];
      #pragma unroll
      for (int i = 0; i < 4; ++i) a4[i] = As[kk][(ty << 2) + i];
      #pragma unroll
      for (int j = 0; j < 4; ++j) b4[j] = Bs[kk][(tx << 2) + j];
      #pragma unroll
      for (int i = 0; i < 4; ++i)
        #pragma unroll
        for (int j = 0; j < 4; ++j) acc[i][j] += a4[i] * b4[j];
    }
    __syncthreads();
  }
  #pragma unroll
  for (int i = 0; i < 4; ++i) {
    int r = row0 + (ty << 2) + i;
    if (r >= N) continue;
    #pragma unroll
    for (int j = 0; j < 4; ++j) {
      int c = col0 + (tx << 2) + j;
      if (c >= Dout) continue;
      float v = acc[i][j] + bias[c];
      if (ACT == 1) v = gelu_exact(v);
      C[(size_t)r * Dout + c] = v;
    }
  }
}

// ---------------------------------------------------------------- complex linear GEMM
// Yr = Zr@Wr^T - Zi@Wi^T              (br cancels in reference)
// Yi = Zr@Wi^T + Zi@Wr^T + 2*bi       (bi added twice in reference)
// N = 8192 rows, K = Dout = 256 (all multiples of 64).
__global__ __launch_bounds__(256) void clin_gemm(const float* __restrict__ Zr,
    const float* __restrict__ Zi, const float* __restrict__ Wr, const float* __restrict__ Wi,
    const float* __restrict__ bi, float* __restrict__ Yr, float* __restrict__ Yi) {
  __shared__ float Ar[16][64], Ai[16][64], Br[16][64], Bi[16][64];
  const int tid = threadIdx.x;
  const int row0 = blockIdx.y * 64;
  const int col0 = blockIdx.x * 64;
  const int lr = tid >> 2;
  const int lk = (tid & 3) << 2;
  const int tx = tid & 15, ty = tid >> 4;
  float accr[4][4] = {{0.f}}, acci[4][4] = {{0.f}};
  for (int k0 = 0; k0 < 256; k0 += 16) {
    int arow = row0 + lr, wrow = col0 + lr;
    float4 zrv = *reinterpret_cast<const float4*>(Zr + (size_t)arow * 256 + k0 + lk);
    float4 ziv = *reinterpret_cast<const float4*>(Zi + (size_t)arow * 256 + k0 + lk);
    float4 wrv = *reinterpret_cast<const float4*>(Wr + (size_t)wrow * 256 + k0 + lk);
    float4 wiv = *reinterpret_cast<const float4*>(Wi + (size_t)wrow * 256 + k0 + lk);
    Ar[lk + 0][lr] = zrv.x; Ar[lk + 1][lr] = zrv.y; Ar[lk + 2][lr] = zrv.z; Ar[lk + 3][lr] = zrv.w;
    Ai[lk + 0][lr] = ziv.x; Ai[lk + 1][lr] = ziv.y; Ai[lk + 2][lr] = ziv.z; Ai[lk + 3][lr] = ziv.w;
    Br[lk + 0][lr] = wrv.x; Br[lk + 1][lr] = wrv.y; Br[lk + 2][lr] = wrv.z; Br[lk + 3][lr] = wrv.w;
    Bi[lk + 0][lr] = wiv.x; Bi[lk + 1][lr] = wiv.y; Bi[lk + 2][lr] = wiv.z; Bi[lk + 3][lr] = wiv.w;
    __syncthreads();
    #pragma unroll
    for (int kk = 0; kk < 16; ++kk) {
      float ar4[4], ai4[4], br4[4], bi4[4];
      #pragma unroll
      for (int i = 0; i < 4; ++i) { ar4[i] = Ar[kk][(ty << 2) + i]; ai4[i] = Ai[kk][(ty << 2) + i]; }
      #pragma unroll
      for (int j = 0; j < 4; ++j) { br4[j] = Br[kk][(tx << 2) + j]; bi4[j] = Bi[kk][(tx << 2) + j]; }
      #pragma unroll
      for (int i = 0; i < 4; ++i)
        #pragma unroll
        for (int j = 0; j < 4; ++j) {
          accr[i][j] += ar4[i] * br4[j] - ai4[i] * bi4[j];
          acci[i][j] += ar4[i] * bi4[j] + ai4[i] * br4[j];
        }
    }
    __syncthreads();
  }
  #pragma unroll
  for (int i = 0; i < 4; ++i) {
    int r = row0 + (ty << 2) + i;
    #pragma unroll
    for (int j = 0; j < 4; ++j) {
      int c = col0 + (tx << 2) + j;
      Yr[(size_t)r * 256 + c] = accr[i][j];
      Yi[(size_t)r * 256 + c] = acci[i][j] + 2.0f * bi[c];
    }
  }
}

// ---------------------------------------------------------------- DFT along T (rfft)
// Zr[b,f,d] = sum_t x[b,t,d] cos(2 pi f t / 63); Zi = -sum_t x sin(...)
__global__ __launch_bounds__(256) void dft_kernel(const float* __restrict__ X,
    float* __restrict__ Zr, float* __restrict__ Zi) {
  __shared__ float cs[T_], sn[T_];
  int b = blockIdx.x >> 5, f = blockIdx.x & 31;
  if (threadIdx.x < T_) {
    int ft = (f * threadIdx.x) % T_;
    float ang = (6.283185307179586f / 63.0f) * (float)ft;
    sincosf(ang, &sn[threadIdx.x], &cs[threadIdx.x]);
  }
  __syncthreads();
  int d = threadIdx.x;
  const float* xb = X + (size_t)b * T_ * D_ + d;
  float ar = 0.f, ai = 0.f;
  for (int t = 0; t < T_; ++t) {
    float v = xb[(size_t)t * D_];
    ar = fmaf(v, cs[t], ar);
    ai = fmaf(-v, sn[t], ai);
  }
  size_t o = (size_t)b * F_ * D_ + (size_t)f * D_ + d;
  Zr[o] = ar;
  Zi[o] = ai;
}

// ---------------------------------------------------------------- softshrink on complex mag
__global__ __launch_bounds__(256) void shrink_kernel(float* __restrict__ zr,
                                                     float* __restrict__ zi, int n) {
  int i = blockIdx.x * 256 + threadIdx.x;
  if (i >= n) return;
  float r = zr[i], im = zi[i];
  float mag = sqrtf(r * r + im * im);
  float s = (mag > LAM_) ? (mag - LAM_) / (mag + 1e-8f) : 0.0f;
  zr[i] = r * s;
  zi[i] = im * s;
}

// ---------------------------------------------------------------- irfft (n=63, odd) * g
// pt[t] = (1/63)(Re X0 + 2 sum_{f=1..31} (Xr cos - Xi sin));  gp = g * pt
__global__ __launch_bounds__(256) void irfft_mul_kernel(const float* __restrict__ Zr,
    const float* __restrict__ Zi, const float* __restrict__ g, float* __restrict__ gp) {
  __shared__ float cs[F_], sn[F_];
  int row = blockIdx.x;           // b*T_ + t
  int b = row / T_, t = row - b * T_;
  if (threadIdx.x < F_) {
    int ft = (threadIdx.x * t) % T_;
    float ang = (6.283185307179586f / 63.0f) * (float)ft;
    sincosf(ang, &sn[threadIdx.x], &cs[threadIdx.x]);
  }
  __syncthreads();
  int d = threadIdx.x;
  const float* zr = Zr + (size_t)b * F_ * D_ + d;
  const float* zi = Zi + (size_t)b * F_ * D_ + d;
  float acc = zr[0];              // f=0: cos=1, Im(X0) ignored by irfft
  #pragma unroll
  for (int f = 1; f < F_; ++f)
    acc += 2.0f * (zr[(size_t)f * D_] * cs[f] - zi[(size_t)f * D_] * sn[f]);
  size_t idx = (size_t)row * D_ + d;
  gp[idx] = g[idx] * (acc * (1.0f / 63.0f));
}

// ---------------------------------------------------------------- add + layernorm (in-place into x)
__global__ __launch_bounds__(256) void ln_kernel(const float* __restrict__ outb,
    float* __restrict__ x, const float* __restrict__ g, const float* __restrict__ b) {
  __shared__ float red[4];
  size_t base = (size_t)blockIdx.x * D_;
  int d = threadIdx.x;
  float v = outb[base + d] + x[base + d];
  float mu = block_sum256(v, red) * (1.0f / D_);
  float dv = v - mu;
  float var = block_sum256(dv * dv, red) * (1.0f / D_);
  x[base + d] = dv * rsqrtf(var + 1e-5f) * g[d] + b[d];
}

// ---------------------------------------------------------------- gate + blend
__global__ __launch_bounds__(256) void gate_feat_kernel(const float* __restrict__ tb,
    const float* __restrict__ sb, const float* __restrict__ gw, const float* __restrict__ gb,
    float* __restrict__ feat) {
  __shared__ float red[4];
  size_t base = (size_t)blockIdx.x * D_;
  int d = threadIdx.x;
  float tv = tb[base + d];
  float gsum = block_sum256(tv * gw[d], red) + gb[0];
  float gate = 1.0f / (1.0f + expf(-gsum));
  feat[base + d] = gate * tv + (1.0f - gate) * sb[base + d];
}

// ---------------------------------------------------------------- final rescale
__global__ __launch_bounds__(256) void final_kernel(const float* __restrict__ po,
    const float* __restrict__ stdb, const float* __restrict__ meanb, float* __restrict__ y) {
  int i = blockIdx.x * 256 + threadIdx.x;     // 516096 total
  int b = i / (M_ * H_);
  int r = i - b * (M_ * H_);
  int m = r / H_;
  float sc = stdb[b * M_ + m] + 1e-5f;
  y[i] = po[i] * sc + meanb[b * M_ + m];
}

// ---------------------------------------------------------------- launch
extern "C" void kernel_launch(void* const* d_in, const int* in_sizes, int n_in,
                              void* d_out, int out_size, void* d_ws, size_t ws_size,
                              hipStream_t stream) {
  const float* x      = (const float*)d_in[0];
  const float* conv_w = (const float*)d_in[1];
  const float* conv_b = (const float*)d_in[2];
  const float* tP[16];
  const float* sP[16];
  for (int i = 0; i < 16; ++i) tP[i] = (const float*)d_in[3 + i];
  for (int i = 0; i < 16; ++i) sP[i] = (const float*)d_in[19 + i];
  const float* gate_w = (const float*)d_in[35];
  const float* gate_b = (const float*)d_in[36];
  const float* proj_w = (const float*)d_in[37];
  const float* proj_b = (const float*)d_in[38];
  float* out = (float*)d_out;

  float* ws    = (float*)d_ws;
  float* xn    = ws;                       // 2752512
  float* meanb = xn    + 2752512;          // 5376
  float* stdb  = meanb + 5376;             // 5376
  float* tbuf  = stdb  + 5376;             // 4128768
  float* sbuf  = tbuf  + 4128768;          // 4128768
  float* g1    = sbuf  + 4128768;          // 8257536 (gelu hidden / im2col / gp / proj_out)
  float* g     = g1    + 8257536;          // 4128768 (mlp out / feat)
  float* zr0   = g     + 4128768;          // 2097152
  float* zi0   = zr0   + 2097152;          // 2097152 (zr0+zi0 doubles as outb: 4128768)
  float* zr1   = zi0   + 2097152;          // 2097152
  float* zi1   = zr1   + 2097152;          // 2097152
  // total 31795712 floats = ~121.3 MiB

  norm_kernel<<<B_ * M_, 256, 0, stream>>>(x, xn, meanb, stdb);
  im2col_kernel<<<NT_, 256, 0, stream>>>(xn, g1);
  gemm_bias<0><<<dim3(D_ / 64, NT_ / 64), 256, 0, stream>>>(g1, conv_w, conv_b, g, NT_, KC_, D_);
  add_pe_kernel<<<NT_, 256, 0, stream>>>(g, tbuf, sbuf);

  for (int tower = 0; tower < 2; ++tower) {
    float* xb = (tower == 0) ? tbuf : sbuf;
    const float** Pp = (tower == 0) ? tP : sP;
    for (int l = 0; l < 3; ++l) {
      const float* Tw   = Pp[0]  + (size_t)l * D_ * D_;
      const float* Tb   = Pp[1]  + (size_t)l * D_;
      const float* Gew  = Pp[2]  + (size_t)l * HID_ * D_;
      const float* Geb  = Pp[3]  + (size_t)l * HID_;
      const float* Gpw  = Pp[4]  + (size_t)l * D_ * HID_;
      const float* Gpb  = Pp[5]  + (size_t)l * D_;
      const float* H1Wr = Pp[6]  + (size_t)l * D_ * D_;
      const float* H1Wi = Pp[7]  + (size_t)l * D_ * D_;
      const float* H1bi = Pp[9]  + (size_t)l * D_;
      const float* H2Wr = Pp[10] + (size_t)l * D_ * D_;
      const float* H2Wi = Pp[11] + (size_t)l * D_ * D_;
      const float* H2bi = Pp[13] + (size_t)l * D_;
      const float* lng  = Pp[14] + (size_t)l * D_;
      const float* lnb  = Pp[15] + (size_t)l * D_;

      // g = gelu(x @ Gew^T + Geb) @ Gpw^T + Gpb
      gemm_bias<1><<<dim3(HID_ / 64, NT_ / 64), 256, 0, stream>>>(xb, Gew, Geb, g1, NT_, D_, HID_);
      gemm_bias<0><<<dim3(D_ / 64, NT_ / 64), 256, 0, stream>>>(g1, Gpw, Gpb, g, NT_, HID_, D_);
      // frequency branch
      dft_kernel<<<B_ * F_, 256, 0, stream>>>(xb, zr0, zi0);
      clin_gemm<<<dim3(D_ / 64, (B_ * F_) / 64), 256, 0, stream>>>(zr0, zi0, H1Wr, H1Wi, H1bi, zr1, zi1);
      shrink_kernel<<<(B_ * F_ * D_) / 256, 256, 0, stream>>>(zr1, zi1, B_ * F_ * D_);
      clin_gemm<<<dim3(D_ / 64, (B_ * F_) / 64), 256, 0, stream>>>(zr1, zi1, H2Wr, H2Wi, H2bi, zr0, zi0);
      irfft_mul_kernel<<<NT_, 256, 0, stream>>>(zr0, zi0, g, g1);   // gp -> g1
      // out = gp @ Tw^T + Tb  (into zr0+zi0 region), then x = LN(out + x)
      gemm_bias<0><<<dim3(D_ / 64, NT_ / 64), 256, 0, stream>>>(g1, Tw, Tb, zr0, NT_, D_, D_);
      ln_kernel<<<NT_, 256, 0, stream>>>(zr0, xb, lng, lnb);
    }
  }

  gate_feat_kernel<<<NT_, 256, 0, stream>>>(tbuf, sbuf, gate_w, gate_b, g);
  gemm_bias<0><<<dim3((M_ * H_ + 63) / 64, B_ / 64), 256, 0, stream>>>(g, proj_w, proj_b, g1,
                                                                      B_, NT_, M_ * H_);
  final_kernel<<<(B_ * M_ * H_) / 256, 256, 0, stream>>>(g1, stdb, meanb, out);
}

// Round 2
// 1673.089 us; speedup vs baseline: 2.4550x; 2.4550x over previous
//
#include <hip/hip_runtime.h>
#include <cstddef>
#include <cstdint>

#define B_    256
#define M_    21
#define L_    512
#define D_    256
#define T_    63
#define F_    32
#define NT_   16128   // B_*T_
#define HID_  512
#define KCP_  352     // M_*P_=336 padded to 32
#define H_    96
#define LAM_  0.01f

typedef __attribute__((ext_vector_type(8))) short short8;
typedef __attribute__((ext_vector_type(4))) float f32x4;
typedef unsigned int u32;
typedef const u32 __attribute__((address_space(1)))* gas1_t;
typedef u32 __attribute__((address_space(3)))* las3_t;

// async global->LDS, 16B/lane; LDS dest = wave-uniform base + lane*16
__device__ __forceinline__ void async_copy16(const void* g, void* l) {
  __builtin_amdgcn_global_load_lds((gas1_t)g, (las3_t)(uintptr_t)l, 16, 0, 0);
}

__device__ __forceinline__ unsigned short f2bf(float x) {   // RNE
  unsigned u = __float_as_uint(x);
  return (unsigned short)((u + 0x7FFF + ((u >> 16) & 1)) >> 16);
}
__device__ __forceinline__ float bf2f(unsigned short u) {
  return __uint_as_float(((unsigned)u) << 16);
}
__device__ __forceinline__ float gelu_exact(float v) {
  return 0.5f * v * (1.0f + erff(v * 0.70710678118654752f));
}
__device__ __forceinline__ float block_sum256(float v, float* red4) {
  #pragma unroll
  for (int off = 32; off > 0; off >>= 1) v += __shfl_down(v, off, 64);
  if ((threadIdx.x & 63) == 0) red4[threadIdx.x >> 6] = v;
  __syncthreads();
  float r = red4[0] + red4[1] + red4[2] + red4[3];
  __syncthreads();
  return r;
}

// ---------------------------------------------------------------- weight prep (fp32 -> bf16, col pad)
struct CvtEnt { const float* src; unsigned short* dst; int rows, scol, dcol, blk0; };
struct CvtArgs { CvtEnt e[19]; int nent; };
__global__ __launch_bounds__(256) void wprep_kernel(CvtArgs a) {
  int blk = blockIdx.x, e = 0;
  while (e + 1 < a.nent && a.e[e + 1].blk0 <= blk) ++e;
  CvtEnt en = a.e[e];
  int idx = (blk - en.blk0) * 256 + threadIdx.x;
  int total = en.rows * en.dcol;
  if (idx >= total) return;
  int r = idx / en.dcol, c = idx - r * en.dcol;
  float v = (c < en.scol) ? en.src[(size_t)r * en.scol + c] : 0.f;
  en.dst[idx] = f2bf(v);
}

// build [[Wr|-Wi],[Wi|Wr]] 512x512 bf16 per (tower,layer,h)
struct CatArgs { const float* wr[12]; const float* wi[12]; };
__global__ __launch_bounds__(256) void wcat_kernel(CatArgs a, unsigned short* dst) {
  int e = blockIdx.x >> 10;
  int idx = ((blockIdx.x & 1023) << 8) + threadIdx.x;
  int r = idx >> 9, c = idx & 511;
  const float* wr = a.wr[e];
  const float* wi = a.wi[e];
  float v;
  if (r < 256) v = (c < 256) ? wr[r * 256 + c] : -wi[r * 256 + (c - 256)];
  else         v = (c < 256) ? wi[(r - 256) * 256 + c] : wr[(r - 256) * 256 + (c - 256)];
  dst[(size_t)e * 262144 + idx] = f2bf(v);
}

// ---------------------------------------------------------------- MFMA GEMM: C = A(bf16,NxK) @ W^T + bias
// 128x128 tile, 4 waves (2x2), each wave 4x4 of 16x16x32-bf16 MFMA.
// BIASM: 0 normal, 1 clin (col<256 ? 0 : 2*bi[col-256]), 2 none.
// CVTW: stage W from fp32 with in-register bf16 convert (proj). SPLITK: z = k-chunk.
template <int ACT, int OUTBF, int BIASM, int SPLITK, int CVTW>
__global__ __launch_bounds__(256) void mm_kernel(const unsigned short* __restrict__ A,
    const unsigned short* __restrict__ Wb, const float* __restrict__ Wf,
    const float* __restrict__ bias, void* __restrict__ Cv,
    int N, int K, int Dout, int ksteps) {
  __shared__ __align__(16) unsigned short As[128 * 32];
  __shared__ __align__(16) unsigned short Bs[128 * 32];
  const int tid = threadIdx.x, w = tid >> 6, lane = tid & 63;
  const int quad = lane >> 4, r16 = lane & 15;
  const int kst = SPLITK ? (int)blockIdx.z * ksteps * 32 : 0;

  const unsigned short* gA = A + (size_t)(blockIdx.y * 128 + w * 32 + (lane >> 2)) * K
                               + kst + (lane & 3) * 8;
  unsigned short* lA = As + (w * 32) * 32;
  const unsigned short* gB = nullptr;
  unsigned short* lB = Bs + (w * 32) * 32;
  if (!CVTW) gB = Wb + (size_t)(blockIdx.x * 128 + w * 32 + (lane >> 2)) * K
                     + kst + (lane & 3) * 8;

  f32x4 acc[4][4];
  #pragma unroll
  for (int i = 0; i < 4; ++i)
    #pragma unroll
    for (int j = 0; j < 4; ++j)
      #pragma unroll
      for (int r = 0; r < 4; ++r) acc[i][j][r] = 0.f;

  for (int ks = 0; ks < ksteps; ++ks) {
    async_copy16(gA, lA);
    async_copy16(gA + (size_t)16 * K, lA + 16 * 32);
    if (!CVTW) {
      async_copy16(gB, lB);
      async_copy16(gB + (size_t)16 * K, lB + 16 * 32);
      gB += 32;
    } else {
      int rowW = tid >> 1, halfk = (tid & 1) << 4;
      int wrow = blockIdx.x * 128 + rowW;
      if (wrow >= Dout) wrow = Dout - 1;
      const float* wsrc = Wf + (size_t)wrow * K + kst + ks * 32 + halfk;
      union { unsigned short u[16]; uint4 q[2]; } pk;
      #pragma unroll
      for (int n = 0; n < 16; n += 4) {
        float4 v = *reinterpret_cast<const float4*>(wsrc + n);
        pk.u[n] = f2bf(v.x); pk.u[n + 1] = f2bf(v.y);
        pk.u[n + 2] = f2bf(v.z); pk.u[n + 3] = f2bf(v.w);
      }
      uint4* bd = reinterpret_cast<uint4*>(Bs + rowW * 32 + halfk);
      bd[0] = pk.q[0]; bd[1] = pk.q[1];
    }
    gA += 32;
    __syncthreads();
    const unsigned short* pa = As + (64 * (w >> 1) + r16) * 32 + quad * 8;
    const unsigned short* pb = Bs + (64 * (w & 1) + r16) * 32 + quad * 8;
    short8 af[4], bfv[4];
    #pragma unroll
    for (int i = 0; i < 4; ++i) af[i] = *reinterpret_cast<const short8*>(pa + i * 512);
    #pragma unroll
    for (int j = 0; j < 4; ++j) bfv[j] = *reinterpret_cast<const short8*>(pb + j * 512);
    #pragma unroll
    for (int i = 0; i < 4; ++i)
      #pragma unroll
      for (int j = 0; j < 4; ++j)
        acc[i][j] = __builtin_amdgcn_mfma_f32_16x16x32_bf16(af[i], bfv[j], acc[i][j], 0, 0, 0);
    __syncthreads();
  }

  float* Cf = (float*)Cv;
  unsigned short* Cb = (unsigned short*)Cv;
  if (SPLITK) Cf += (size_t)blockIdx.z * N * Dout;
  const int colb = blockIdx.x * 128 + 64 * (w & 1) + r16;
  const int rowb = blockIdx.y * 128 + 64 * (w >> 1) + quad * 4;
  #pragma unroll
  for (int j = 0; j < 4; ++j) {
    int col = colb + 16 * j;
    if (col >= Dout) continue;
    float bv = 0.f;
    if (BIASM == 0) bv = bias[col];
    else if (BIASM == 1) bv = (col < 256) ? 0.f : 2.0f * bias[col - 256];
    #pragma unroll
    for (int i = 0; i < 4; ++i) {
      #pragma unroll
      for (int r = 0; r < 4; ++r) {
        int row = rowb + 16 * i + r;
        float v = acc[i][j][r] + bv;
        if (ACT == 1) v = gelu_exact(v);
        if (OUTBF) Cb[(size_t)row * Dout + col] = f2bf(v);
        else       Cf[(size_t)row * Dout + col] = v;
      }
    }
  }
}

// ---------------------------------------------------------------- norm
__global__ __launch_bounds__(256) void norm_kernel(const float* __restrict__ x,
    float* __restrict__ xn, float* __restrict__ meanb, float* __restrict__ stdb) {
  __shared__ float red[4];
  int bm = blockIdx.x;
  const float* xr = x + (size_t)bm * L_;
  float v0 = xr[threadIdx.x], v1 = xr[threadIdx.x + 256];
  float mu = block_sum256(v0 + v1, red) * (1.0f / L_);
  float d0 = v0 - mu, d1 = v1 - mu;
  float sd = sqrtf(block_sum256(d0 * d0 + d1 * d1, red) * (1.0f / L_));
  float inv = 1.0f / (sd + 1e-5f);
  float* xo = xn + (size_t)bm * L_;
  xo[threadIdx.x] = d0 * inv;
  xo[threadIdx.x + 256] = d1 * inv;
  if (threadIdx.x == 0) { meanb[bm] = mu; stdb[bm] = sd; }
}

// ---------------------------------------------------------------- im2col -> bf16 padded K=352
__global__ __launch_bounds__(256) void im2col_kernel(const float* __restrict__ xn,
                                                     unsigned short* __restrict__ im) {
  int row = blockIdx.x;
  int b = row / T_, t = row - b * T_;
  const float* xb = xn + (size_t)b * M_ * L_ + t * 8;
  unsigned short* o = im + (size_t)row * KCP_;
  for (int i = threadIdx.x; i < KCP_; i += 256) {
    float v = 0.f;
    if (i < 336) { int m = i >> 4, p = i & 15; v = xb[m * L_ + p]; }
    o[i] = f2bf(v);
  }
}

// ---------------------------------------------------------------- pos-enc + dup (fp32)
__global__ __launch_bounds__(256) void add_pe_kernel(const float* __restrict__ g,
    float* __restrict__ tb, float* __restrict__ sb) {
  int row = blockIdx.x, d = threadIdx.x;
  int t = row % T_;
  size_t idx = (size_t)row * D_ + d;
  float freq = expf((float)(d & ~1) * (-9.210340371976184f / 256.0f));
  float ang = (float)t * freq;
  float pe = (d & 1) ? cosf(ang) : sinf(ang);
  float h = g[idx] + pe;
  tb[idx] = h;
  sb[idx] = h;
}

// ---------------------------------------------------------------- fp32 -> bf16 bulk (float4 granular)
__global__ __launch_bounds__(256) void cvt4_kernel(const float* __restrict__ src,
                                                   unsigned short* __restrict__ dst) {
  int i = blockIdx.x * 256 + threadIdx.x;
  float4 v = reinterpret_cast<const float4*>(src)[i];
  ushort4 o;
  o.x = f2bf(v.x); o.y = f2bf(v.y); o.z = f2bf(v.z); o.w = f2bf(v.w);
  reinterpret_cast<ushort4*>(dst)[i] = o;
}

// ---------------------------------------------------------------- DFT (rfft along T): per-b block, LDS-staged
__global__ __launch_bounds__(256) void dft_kernel(const float* __restrict__ X,
                                                  unsigned short* __restrict__ Zcat) {
  __shared__ float xs[T_ * D_];
  __shared__ float cs63[T_], sn63[T_];
  int b = blockIdx.x;
  const float4* src = reinterpret_cast<const float4*>(X + (size_t)b * T_ * D_);
  for (int i = threadIdx.x; i < T_ * D_ / 4; i += 256)
    reinterpret_cast<float4*>(xs)[i] = src[i];
  if (threadIdx.x < T_) {
    float ang = (6.283185307179586f / 63.0f) * (float)threadIdx.x;
    sincosf(ang, &sn63[threadIdx.x], &cs63[threadIdx.x]);
  }
  __syncthreads();
  int d = threadIdx.x;
  float ar[F_], ai[F_];
  #pragma unroll
  for (int f = 0; f < F_; ++f) { ar[f] = 0.f; ai[f] = 0.f; }
  for (int t = 0; t < T_; ++t) {
    float v = xs[t * D_ + d];
    int k = 0;
    #pragma unroll
    for (int f = 0; f < F_; ++f) {
      ar[f] = fmaf(v, cs63[k], ar[f]);
      ai[f] = fmaf(-v, sn63[k], ai[f]);
      k += t; if (k >= T_) k -= T_;
    }
  }
  unsigned short* z = Zcat + (size_t)b * F_ * 512 + d;
  #pragma unroll
  for (int f = 0; f < F_; ++f) {
    z[(size_t)f * 512]       = f2bf(ar[f]);
    z[(size_t)f * 512 + 256] = f2bf(ai[f]);
  }
}

// ---------------------------------------------------------------- softshrink on bf16 (r,i) pairs, in-place
__global__ __launch_bounds__(256) void shrink_kernel(unsigned short* __restrict__ y) {
  size_t o = (size_t)blockIdx.x * 512 + threadIdx.x;
  float r = bf2f(y[o]), im = bf2f(y[o + 256]);
  float mag = sqrtf(r * r + im * im);
  float s = (mag > LAM_) ? (mag - LAM_) / (mag + 1e-8f) : 0.0f;
  y[o] = f2bf(r * s);
  y[o + 256] = f2bf(im * s);
}

// ---------------------------------------------------------------- irfft(n=63) * g -> bf16; per (b, 9 t's)
__global__ __launch_bounds__(256) void irfft_kernel(const float* __restrict__ Y,
    const float* __restrict__ g, unsigned short* __restrict__ gp) {
  __shared__ float ys[F_ * 512];
  __shared__ float cs63[T_], sn63[T_];
  int b = blockIdx.y, tc = blockIdx.x;  // tc in [0,7): t = tc*9 + tt
  const float4* src = reinterpret_cast<const float4*>(Y + (size_t)b * F_ * 512);
  for (int i = threadIdx.x; i < F_ * 512 / 4; i += 256)
    reinterpret_cast<float4*>(ys)[i] = src[i];
  if (threadIdx.x < T_) {
    float ang = (6.283185307179586f / 63.0f) * (float)threadIdx.x;
    sincosf(ang, &sn63[threadIdx.x], &cs63[threadIdx.x]);
  }
  __syncthreads();
  int d = threadIdx.x;
  for (int tt = 0; tt < 9; ++tt) {
    int t = tc * 9 + tt;
    float acc = ys[d];                 // f=0: Re only (Im(X0) ignored for odd-n irfft)
    int k = t;
    #pragma unroll
    for (int f = 1; f < F_; ++f) {
      acc += 2.0f * (ys[f * 512 + d] * cs63[k] - ys[f * 512 + 256 + d] * sn63[k]);
      k += t; if (k >= T_) k -= T_;
    }
    size_t row = (size_t)b * T_ + t;
    gp[row * D_ + d] = f2bf(g[row * D_ + d] * (acc * (1.0f / 63.0f)));
  }
}

// ---------------------------------------------------------------- add + layernorm; writes fp32 + bf16
__global__ __launch_bounds__(256) void ln_kernel(const float* __restrict__ outb,
    float* __restrict__ x, unsigned short* __restrict__ xbf,
    const float* __restrict__ g, const float* __restrict__ b) {
  __shared__ float red[4];
  size_t base = (size_t)blockIdx.x * D_;
  int d = threadIdx.x;
  float v = outb[base + d] + x[base + d];
  float mu = block_sum256(v, red) * (1.0f / D_);
  float dv = v - mu;
  float var = block_sum256(dv * dv, red) * (1.0f / D_);
  float r = dv * rsqrtf(var + 1e-5f) * g[d] + b[d];
  x[base + d] = r;
  xbf[base + d] = f2bf(r);
}

// ---------------------------------------------------------------- gate + blend -> bf16 feat
__global__ __launch_bounds__(256) void gate_feat_kernel(const float* __restrict__ tb,
    const float* __restrict__ sb, const float* __restrict__ gw, const float* __restrict__ gb,
    unsigned short* __restrict__ featbf) {
  __shared__ float red[4];
  size_t base = (size_t)blockIdx.x * D_;
  int d = threadIdx.x;
  float tv = tb[base + d];
  float gsum = block_sum256(tv * gw[d], red) + gb[0];
  float gate = 1.0f / (1.0f + expf(-gsum));
  featbf[base + d] = f2bf(gate * tv + (1.0f - gate) * sb[base + d]);
}

// ---------------------------------------------------------------- split-K reduce + bias + rescale
__global__ __launch_bounds__(256) void final_kernel(const float* __restrict__ part,
    const float* __restrict__ pb, const float* __restrict__ stdb,
    const float* __restrict__ meanb, float* __restrict__ y) {
  int i = blockIdx.x * 256 + threadIdx.x;         // 516096
  float acc = 0.f;
  #pragma unroll
  for (int z = 0; z < 8; ++z) acc += part[(size_t)z * 516096 + i];
  int b = i / 2016;
  int col = i - b * 2016;
  int m = col / H_;
  float sc = stdb[b * M_ + m] + 1e-5f;
  y[i] = (acc + pb[col]) * sc + meanb[b * M_ + m];
}

// ---------------------------------------------------------------- launch
extern "C" void kernel_launch(void* const* d_in, const int* in_sizes, int n_in,
                              void* d_out, int out_size, void* d_ws, size_t ws_size,
                              hipStream_t stream) {
  const float* x      = (const float*)d_in[0];
  const float* conv_w = (const float*)d_in[1];
  const float* conv_b = (const float*)d_in[2];
  const float* tP[16];
  const float* sP[16];
  for (int i = 0; i < 16; ++i) tP[i] = (const float*)d_in[3 + i];
  for (int i = 0; i < 16; ++i) sP[i] = (const float*)d_in[19 + i];
  const float* gate_w = (const float*)d_in[35];
  const float* gate_b = (const float*)d_in[36];
  const float* proj_w = (const float*)d_in[37];
  const float* proj_b = (const float*)d_in[38];
  float* out = (float*)d_out;

  // ---- workspace layout (floats). total 30,267,904 f = 121.07 MB
  float* ws    = (float*)d_ws;
  float* xn    = ws;                         // 2,752,512
  float* meanb = xn + 2752512;               // 5,376
  float* stdb  = meanb + 5376;               // 5,376
  float* tbuf  = stdb + 5376;                // 4,128,768
  float* sbuf  = tbuf + 4128768;             // 4,128,768
  float* g     = sbuf + 4128768;             // 4,128,768  (mlp out; later: 8 proj partials)
  float* U1    = g + 4128768;                // 4,194,304  (im2col bf16 | hid bf16 | Ycat2 f32)
  float* U2    = U1 + 4194304;               // 4,194,304  (Zcat bf16 + Ycat1 bf16 | outb f32)
  float* U3    = U2 + 4194304;               // 2,064,384  (gp bf16 | featbf bf16)
  float* XBF   = U3 + 2064384;               // 2,064,384  (x bf16, current tower)
  float* WB    = XBF + 2064384;              // 2,600,960  (bf16 weights)

  unsigned short* im2colB = (unsigned short*)U1;
  unsigned short* hidB    = (unsigned short*)U1;
  float*          Ycat2f  = U1;
  unsigned short* Zcat    = (unsigned short*)U2;
  unsigned short* Ycat1   = Zcat + 4194304;
  float*          outb    = U2;
  unsigned short* gp      = (unsigned short*)U3;
  unsigned short* featbf  = (unsigned short*)U3;
  unsigned short* xbf     = (unsigned short*)XBF;
  float*          part    = g;

  unsigned short* wb   = (unsigned short*)WB;
  unsigned short* convW = wb;                         // 256*352 = 90,112
  unsigned short* sets  = wb + 90112;                 // 6 * 327,680 (Gew|Gpw|Tw)
  unsigned short* catW  = wb + 90112 + 1966080;       // 12 * 262,144

  // ---- weight prep
  CvtArgs ca; int blk0 = 0, ne = 0;
  auto add_ent = [&](const float* s, unsigned short* d, int rows, int scol, int dcol) {
    ca.e[ne].src = s; ca.e[ne].dst = d; ca.e[ne].rows = rows;
    ca.e[ne].scol = scol; ca.e[ne].dcol = dcol; ca.e[ne].blk0 = blk0;
    blk0 += (rows * dcol + 255) / 256; ++ne;
  };
  add_ent(conv_w, convW, 256, 336, 352);
  for (int tw = 0; tw < 2; ++tw) {
    const float** Pp = tw ? (const float**)sP : (const float**)tP;
    for (int l = 0; l < 3; ++l) {
      unsigned short* sb = sets + (size_t)(tw * 3 + l) * 327680;
      add_ent(Pp[2] + (size_t)l * 131072, sb,          512, 256, 256);  // Gew
      add_ent(Pp[4] + (size_t)l * 131072, sb + 131072, 256, 512, 512);  // Gpw
      add_ent(Pp[0] + (size_t)l * 65536,  sb + 262144, 256, 256, 256);  // Tw
    }
  }
  ca.nent = ne;
  wprep_kernel<<<blk0, 256, 0, stream>>>(ca);

  CatArgs cat;
  for (int tw = 0; tw < 2; ++tw) {
    const float** Pp = tw ? (const float**)sP : (const float**)tP;
    for (int l = 0; l < 3; ++l) {
      int e0 = (tw * 3 + l) * 2;
      cat.wr[e0]     = Pp[6]  + (size_t)l * 65536;   // H1Wr
      cat.wi[e0]     = Pp[7]  + (size_t)l * 65536;   // H1Wi
      cat.wr[e0 + 1] = Pp[10] + (size_t)l * 65536;   // H2Wr
      cat.wi[e0 + 1] = Pp[11] + (size_t)l * 65536;   // H2Wi
    }
  }
  wcat_kernel<<<12 * 1024, 256, 0, stream>>>(cat, catW);

  // ---- forward
  norm_kernel<<<B_ * M_, 256, 0, stream>>>(x, xn, meanb, stdb);
  im2col_kernel<<<NT_, 256, 0, stream>>>(xn, im2colB);
  mm_kernel<0, 0, 0, 0, 0><<<dim3(2, 126), 256, 0, stream>>>(
      im2colB, convW, nullptr, conv_b, g, NT_, KCP_, D_, KCP_ / 32);
  add_pe_kernel<<<NT_, 256, 0, stream>>>(g, tbuf, sbuf);

  for (int tw = 0; tw < 2; ++tw) {
    float* xb = tw ? sbuf : tbuf;
    const float** Pp = tw ? (const float**)sP : (const float**)tP;
    cvt4_kernel<<<4128768 / 1024, 256, 0, stream>>>(xb, xbf);
    for (int l = 0; l < 3; ++l) {
      unsigned short* sb   = sets + (size_t)(tw * 3 + l) * 327680;
      unsigned short* GewB = sb;
      unsigned short* GpwB = sb + 131072;
      unsigned short* TwB  = sb + 262144;
      unsigned short* cat1 = catW + (size_t)((tw * 3 + l) * 2) * 262144;
      unsigned short* cat2 = cat1 + 262144;
      const float* Tb   = Pp[1]  + (size_t)l * D_;
      const float* Geb  = Pp[3]  + (size_t)l * HID_;
      const float* Gpb  = Pp[5]  + (size_t)l * D_;
      const float* H1bi = Pp[9]  + (size_t)l * D_;
      const float* H2bi = Pp[13] + (size_t)l * D_;
      const float* lng  = Pp[14] + (size_t)l * D_;
      const float* lnb  = Pp[15] + (size_t)l * D_;

      mm_kernel<1, 1, 0, 0, 0><<<dim3(4, 126), 256, 0, stream>>>(
          xbf, GewB, nullptr, Geb, hidB, NT_, 256, 512, 8);
      mm_kernel<0, 0, 0, 0, 0><<<dim3(2, 126), 256, 0, stream>>>(
          hidB, GpwB, nullptr, Gpb, g, NT_, 512, 256, 16);
      dft_kernel<<<B_, 256, 0, stream>>>(xb, Zcat);
      mm_kernel<0, 1, 1, 0, 0><<<dim3(4, 64), 256, 0, stream>>>(
          Zcat, cat1, nullptr, H1bi, Ycat1, B_ * F_, 512, 512, 16);
      shrink_kernel<<<B_ * F_, 256, 0, stream>>>(Ycat1);
      mm_kernel<0, 0, 1, 0, 0><<<dim3(4, 64), 256, 0, stream>>>(
          Ycat1, cat2, nullptr, H2bi, Ycat2f, B_ * F_, 512, 512, 16);
      irfft_kernel<<<dim3(7, B_), 256, 0, stream>>>(Ycat2f, g, gp);
      mm_kernel<0, 0, 0, 0, 0><<<dim3(2, 126), 256, 0, stream>>>(
          gp, TwB, nullptr, Tb, outb, NT_, 256, 256, 8);
      ln_kernel<<<NT_, 256, 0, stream>>>(outb, xb, xbf, lng, lnb);
    }
  }

  gate_feat_kernel<<<NT_, 256, 0, stream>>>(tbuf, sbuf, gate_w, gate_b, featbf);
  mm_kernel<0, 0, 2, 1, 1><<<dim3(16, 2, 8), 256, 0, stream>>>(
      featbf, nullptr, proj_w, nullptr, part, B_, NT_, 2016, 63);
  final_kernel<<<2016, 256, 0, stream>>>(part, proj_b, stdb, meanb, out);
}

// Round 3
// 1313.602 us; speedup vs baseline: 3.1268x; 1.2737x over previous
//
#include <hip/hip_runtime.h>
#include <cstddef>
#include <cstdint>

#define B_    256
#define M_    21
#define L_    512
#define D_    256
#define T_    63
#define F_    32
#define NT_   16128   // B_*T_
#define HID_  512
#define KCP_  352     // M_*P_=336 padded to 32
#define H_    96
#define LAM_  0.01f
#define PZ_   12      // proj split-K factor

typedef __attribute__((ext_vector_type(8))) short short8;
typedef __attribute__((ext_vector_type(4))) float f32x4;
typedef unsigned int u32;
typedef const u32 __attribute__((address_space(1)))* gas1_t;
typedef u32 __attribute__((address_space(3)))* las3_t;

__device__ __forceinline__ void async_copy16(const void* g, void* l) {
  __builtin_amdgcn_global_load_lds((gas1_t)g, (las3_t)(uintptr_t)l, 16, 0, 0);
}
__device__ __forceinline__ unsigned short f2bf(float x) {   // RNE
  unsigned u = __float_as_uint(x);
  return (unsigned short)((u + 0x7FFF + ((u >> 16) & 1)) >> 16);
}
__device__ __forceinline__ float bf2f(unsigned short u) {
  return __uint_as_float(((unsigned)u) << 16);
}
__device__ __forceinline__ float gelu_exact(float v) {
  return 0.5f * v * (1.0f + erff(v * 0.70710678118654752f));
}
__device__ __forceinline__ float block_sum256(float v, float* red4) {
  #pragma unroll
  for (int off = 32; off > 0; off >>= 1) v += __shfl_down(v, off, 64);
  if ((threadIdx.x & 63) == 0) red4[threadIdx.x >> 6] = v;
  __syncthreads();
  float r = red4[0] + red4[1] + red4[2] + red4[3];
  __syncthreads();
  return r;
}

// ---------------------------------------------------------------- weight prep
struct CvtEnt { const float* src; unsigned short* dst; int rows, scol, dcol, blk0; };
struct CvtArgs { CvtEnt e[19]; int nent; };
__global__ __launch_bounds__(256) void wprep_kernel(CvtArgs a) {
  int blk = blockIdx.x, e = 0;
  while (e + 1 < a.nent && a.e[e + 1].blk0 <= blk) ++e;
  CvtEnt en = a.e[e];
  int idx = (blk - en.blk0) * 256 + threadIdx.x;
  int total = en.rows * en.dcol;
  if (idx >= total) return;
  int r = idx / en.dcol, c = idx - r * en.dcol;
  float v = (c < en.scol) ? en.src[(size_t)r * en.scol + c] : 0.f;
  en.dst[idx] = f2bf(v);
}

// interleaved cat weight: row 2c+p, col 2d+q
// p=0 (yr): q=0 -> Wr[c,d], q=1 -> -Wi[c,d]
// p=1 (yi): q=0 -> Wi[c,d], q=1 ->  Wr[c,d]
struct CatArgs { const float* wr[12]; const float* wi[12]; };
__global__ __launch_bounds__(256) void wcat_kernel(CatArgs a, unsigned short* dst) {
  int e = blockIdx.x >> 10;
  int idx = ((blockIdx.x & 1023) << 8) + threadIdx.x;
  int r = idx >> 9, c = idx & 511;
  int cp = r >> 1, p = r & 1, d = c >> 1, q = c & 1;
  const float* wr = a.wr[e];
  const float* wi = a.wi[e];
  float v;
  if (p == 0) v = (q == 0) ? wr[cp * 256 + d] : -wi[cp * 256 + d];
  else        v = (q == 0) ? wi[cp * 256 + d] :  wr[cp * 256 + d];
  dst[(size_t)e * 262144 + idx] = f2bf(v);
}

// ---------------------------------------------------------------- MFMA GEMM
// C = A @ W^T (+bias). 128x128 tile, 4 waves, 4x4 16x16x32-bf16 MFMA each.
// Tower select: blockIdx.y >= yhalf -> W1/b1.
// BIASM: 0 normal, 1 interleaved clin (odd col: 2*bi[col>>1]), 2 none(+col guard).
// CVTA: stage A from fp32. CVTW: stage W from fp32. SHRINK: softshrink via shfl_xor.
// MULPT: epilogue *= pt[row,col] (bf16). SPLITK: partials at z*prow*Dout.
template <int ACT, int OUTBF, int BIASM, int KSTEPS, int CVTA, int CVTW,
          int SHRINK, int MULPT, int SPLITK>
__global__ __launch_bounds__(256) void mm_kernel(
    const void* __restrict__ Av,
    const unsigned short* __restrict__ W0, const unsigned short* __restrict__ W1,
    const float* __restrict__ Wf,
    const float* __restrict__ b0, const float* __restrict__ b1,
    const unsigned short* __restrict__ ptb,
    void* __restrict__ Cv,
    const int K, const int Dout, const int ksteps_rt, const int yhalf, const int prow) {
  __shared__ __align__(16) unsigned short As[128 * 32];
  __shared__ __align__(16) unsigned short Bs[128 * 32];
  const int ksteps = KSTEPS ? KSTEPS : ksteps_rt;
  const int tid = threadIdx.x, w = tid >> 6, lane = tid & 63;
  const int quad = lane >> 4, r16 = lane & 15;
  const int kst = SPLITK ? (int)blockIdx.z * ksteps * 32 : 0;
  const int tower = ((int)blockIdx.y >= yhalf) ? 1 : 0;
  const unsigned short* Wb = tower ? W1 : W0;
  const float* bias = tower ? b1 : b0;

  const unsigned short* Ab = (const unsigned short*)Av;
  const float* Af = (const float*)Av;
  const unsigned short* gA = nullptr;
  unsigned short* lA = As + (w * 32) * 32;
  if (!CVTA) gA = Ab + (size_t)(blockIdx.y * 128 + w * 32 + (lane >> 2)) * K
                     + kst + (lane & 3) * 8;
  const unsigned short* gB = nullptr;
  unsigned short* lB = Bs + (w * 32) * 32;
  if (!CVTW) gB = Wb + (size_t)(blockIdx.x * 128 + w * 32 + (lane >> 2)) * K
                     + kst + (lane & 3) * 8;

  f32x4 acc[4][4];
  #pragma unroll
  for (int i = 0; i < 4; ++i)
    #pragma unroll
    for (int j = 0; j < 4; ++j)
      #pragma unroll
      for (int r = 0; r < 4; ++r) acc[i][j][r] = 0.f;

  for (int ks = 0; ks < ksteps; ++ks) {
    if (!CVTA) {
      async_copy16(gA, lA);
      async_copy16(gA + (size_t)16 * K, lA + 16 * 32);
      gA += 32;
    } else {
      int rowA = tid >> 1, halfk = (tid & 1) << 4;
      const float* asrc = Af + (size_t)((int)blockIdx.y * 128 + rowA) * K + ks * 32 + halfk;
      union { unsigned short u[16]; uint4 q[2]; } pk;
      #pragma unroll
      for (int n = 0; n < 16; n += 4) {
        float4 v = *reinterpret_cast<const float4*>(asrc + n);
        pk.u[n] = f2bf(v.x); pk.u[n + 1] = f2bf(v.y);
        pk.u[n + 2] = f2bf(v.z); pk.u[n + 3] = f2bf(v.w);
      }
      uint4* ad = reinterpret_cast<uint4*>(As + rowA * 32 + halfk);
      ad[0] = pk.q[0]; ad[1] = pk.q[1];
    }
    if (!CVTW) {
      async_copy16(gB, lB);
      async_copy16(gB + (size_t)16 * K, lB + 16 * 32);
      gB += 32;
    } else {
      int rowW = tid >> 1, halfk = (tid & 1) << 4;
      int wrow = blockIdx.x * 128 + rowW;
      if (wrow >= Dout) wrow = Dout - 1;
      const float* wsrc = Wf + (size_t)wrow * K + kst + ks * 32 + halfk;
      union { unsigned short u[16]; uint4 q[2]; } pk;
      #pragma unroll
      for (int n = 0; n < 16; n += 4) {
        float4 v = *reinterpret_cast<const float4*>(wsrc + n);
        pk.u[n] = f2bf(v.x); pk.u[n + 1] = f2bf(v.y);
        pk.u[n + 2] = f2bf(v.z); pk.u[n + 3] = f2bf(v.w);
      }
      uint4* bd = reinterpret_cast<uint4*>(Bs + rowW * 32 + halfk);
      bd[0] = pk.q[0]; bd[1] = pk.q[1];
    }
    __syncthreads();
    const unsigned short* pa = As + (64 * (w >> 1) + r16) * 32 + quad * 8;
    const unsigned short* pb = Bs + (64 * (w & 1) + r16) * 32 + quad * 8;
    short8 af[4], bfv[4];
    #pragma unroll
    for (int i = 0; i < 4; ++i) af[i] = *reinterpret_cast<const short8*>(pa + i * 512);
    #pragma unroll
    for (int j = 0; j < 4; ++j) bfv[j] = *reinterpret_cast<const short8*>(pb + j * 512);
    #pragma unroll
    for (int i = 0; i < 4; ++i)
      #pragma unroll
      for (int j = 0; j < 4; ++j)
        acc[i][j] = __builtin_amdgcn_mfma_f32_16x16x32_bf16(af[i], bfv[j], acc[i][j], 0, 0, 0);
    __syncthreads();
  }

  float* Cf = (float*)Cv;
  unsigned short* Cb = (unsigned short*)Cv;
  if (SPLITK) Cf += (size_t)blockIdx.z * prow * Dout;
  const int colb = blockIdx.x * 128 + 64 * (w & 1) + r16;
  const int rowb = blockIdx.y * 128 + 64 * (w >> 1) + quad * 4;
  #pragma unroll
  for (int j = 0; j < 4; ++j) {
    int col = colb + 16 * j;
    float bv = 0.f;
    if (BIASM == 0) bv = bias[col];
    else if (BIASM == 1) bv = (col & 1) ? 2.0f * bias[col >> 1] : 0.f;
    bool colok = (BIASM != 2) || (col < Dout);
    #pragma unroll
    for (int i = 0; i < 4; ++i) {
      #pragma unroll
      for (int r = 0; r < 4; ++r) {
        int row = rowb + 16 * i + r;
        float v = acc[i][j][r] + bv;
        if (ACT == 1) v = gelu_exact(v);
        if (SHRINK) {
          float o = __shfl_xor(v, 1, 64);
          float mag = sqrtf(v * v + o * o);
          float s = (mag > LAM_) ? (mag - LAM_) / (mag + 1e-8f) : 0.f;
          v *= s;
        }
        if (MULPT) v *= bf2f(ptb[(size_t)row * Dout + col]);
        if (colok) {
          if (OUTBF) Cb[(size_t)row * Dout + col] = f2bf(v);
          else       Cf[(size_t)row * Dout + col] = v;
        }
      }
    }
  }
}

// ---------------------------------------------------------------- norm
__global__ __launch_bounds__(256) void norm_kernel(const float* __restrict__ x,
    float* __restrict__ xn, float* __restrict__ meanb, float* __restrict__ stdb) {
  __shared__ float red[4];
  int bm = blockIdx.x;
  const float* xr = x + (size_t)bm * L_;
  float v0 = xr[threadIdx.x], v1 = xr[threadIdx.x + 256];
  float mu = block_sum256(v0 + v1, red) * (1.0f / L_);
  float d0 = v0 - mu, d1 = v1 - mu;
  float sd = sqrtf(block_sum256(d0 * d0 + d1 * d1, red) * (1.0f / L_));
  float inv = 1.0f / (sd + 1e-5f);
  float* xo = xn + (size_t)bm * L_;
  xo[threadIdx.x] = d0 * inv;
  xo[threadIdx.x + 256] = d1 * inv;
  if (threadIdx.x == 0) { meanb[bm] = mu; stdb[bm] = sd; }
}

// ---------------------------------------------------------------- im2col -> bf16 K=352
__global__ __launch_bounds__(256) void im2col_kernel(const float* __restrict__ xn,
                                                     unsigned short* __restrict__ im) {
  int row = blockIdx.x;
  int b = row / T_, t = row - b * T_;
  const float* xb = xn + (size_t)b * M_ * L_ + t * 8;
  unsigned short* o = im + (size_t)row * KCP_;
  for (int i = threadIdx.x; i < KCP_; i += 256) {
    float v = 0.f;
    if (i < 336) { int m = i >> 4, p = i & 15; v = xb[m * L_ + p]; }
    o[i] = f2bf(v);
  }
}

// ---------------------------------------------------------------- pos-enc + dup into both towers
__global__ __launch_bounds__(256) void add_pe_kernel(const float* __restrict__ g0,
                                                     float* __restrict__ x32) {
  int row = blockIdx.x, d = threadIdx.x;
  int t = row % T_;
  size_t idx = (size_t)row * D_ + d;
  float freq = expf((float)(d & ~1) * (-9.210340371976184f / 256.0f));
  float ang = (float)t * freq;
  float pe = (d & 1) ? cosf(ang) : sinf(ang);
  float h = g0[idx] + pe;
  x32[idx] = h;
  x32[idx + (size_t)NT_ * D_] = h;
}

// ---------------------------------------------------------------- DFT along T (rfft), interleaved packed out
__global__ __launch_bounds__(256) void dft_kernel(const float* __restrict__ X,
                                                  unsigned short* __restrict__ Zcat) {
  __shared__ float xs[T_ * D_];
  __shared__ float cs63[T_], sn63[T_];
  int bt = blockIdx.x;                  // tower*B + b
  const float4* src = reinterpret_cast<const float4*>(X + (size_t)bt * T_ * D_);
  for (int i = threadIdx.x; i < T_ * D_ / 4; i += 256)
    reinterpret_cast<float4*>(xs)[i] = src[i];
  if (threadIdx.x < T_) {
    float ang = (6.283185307179586f / 63.0f) * (float)threadIdx.x;
    sincosf(ang, &sn63[threadIdx.x], &cs63[threadIdx.x]);
  }
  __syncthreads();
  int d = threadIdx.x;
  float ar[F_], ai[F_];
  #pragma unroll
  for (int f = 0; f < F_; ++f) { ar[f] = 0.f; ai[f] = 0.f; }
  for (int t = 0; t < T_; ++t) {
    float v = xs[t * D_ + d];
    int k = 0;
    #pragma unroll
    for (int f = 0; f < F_; ++f) {
      ar[f] = fmaf(v, cs63[k], ar[f]);
      ai[f] = fmaf(-v, sn63[k], ai[f]);
      k += t; if (k >= T_) k -= T_;
    }
  }
  u32* z = reinterpret_cast<u32*>(Zcat + (size_t)bt * F_ * 512);
  #pragma unroll
  for (int f = 0; f < F_; ++f) {
    u32 pr = f2bf(ar[f]), pi = f2bf(ai[f]);
    z[f * 256 + d] = pr | (pi << 16);
  }
}

// ---------------------------------------------------------------- irfft(n=63) -> pt bf16
__global__ __launch_bounds__(256) void irfft_kernel(const float* __restrict__ Y,
                                                    unsigned short* __restrict__ ptb) {
  __shared__ float yr[F_ * 256], yi[F_ * 256];
  __shared__ float cs63[T_], sn63[T_];
  int bt = blockIdx.y, tc = blockIdx.x;      // grid (7, 512)
  const float4* src = reinterpret_cast<const float4*>(Y + (size_t)bt * F_ * 512);
  for (int q = threadIdx.x; q < F_ * 128; q += 256) {
    float4 v = src[q];
    int f = q >> 7, dq = (q & 127) << 1;
    yr[f * 256 + dq] = v.x;     yi[f * 256 + dq] = v.y;
    yr[f * 256 + dq + 1] = v.z; yi[f * 256 + dq + 1] = v.w;
  }
  if (threadIdx.x < T_) {
    float ang = (6.283185307179586f / 63.0f) * (float)threadIdx.x;
    sincosf(ang, &sn63[threadIdx.x], &cs63[threadIdx.x]);
  }
  __syncthreads();
  int d = threadIdx.x;
  for (int tt = 0; tt < 9; ++tt) {
    int t = tc * 9 + tt;
    float acc = yr[d];                       // f=0: Re only (odd-n irfft ignores Im(X0))
    int k = t;
    #pragma unroll
    for (int f = 1; f < F_; ++f) {
      acc += 2.0f * (yr[f * 256 + d] * cs63[k] - yi[f * 256 + d] * sn63[k]);
      k += t; if (k >= T_) k -= T_;
    }
    ptb[((size_t)bt * T_ + t) * D_ + d] = f2bf(acc * (1.0f / 63.0f));
  }
}

// ---------------------------------------------------------------- add + layernorm (in-place x32)
__global__ __launch_bounds__(256) void ln_kernel(const float* __restrict__ outb,
    float* __restrict__ x, const float* __restrict__ g0, const float* __restrict__ b0,
    const float* __restrict__ g1, const float* __restrict__ b1, int yhalf) {
  __shared__ float red[4];
  size_t base = (size_t)blockIdx.x * D_;
  const float* g = ((int)blockIdx.x >= yhalf) ? g1 : g0;
  const float* b = ((int)blockIdx.x >= yhalf) ? b1 : b0;
  int d = threadIdx.x;
  float v = outb[base + d] + x[base + d];
  float mu = block_sum256(v, red) * (1.0f / D_);
  float dv = v - mu;
  float var = block_sum256(dv * dv, red) * (1.0f / D_);
  x[base + d] = dv * rsqrtf(var + 1e-5f) * g[d] + b[d];
}

// ---------------------------------------------------------------- gate + blend -> bf16 feat
__global__ __launch_bounds__(256) void gate_feat_kernel(const float* __restrict__ x32,
    const float* __restrict__ gw, const float* __restrict__ gb,
    unsigned short* __restrict__ featbf) {
  __shared__ float red[4];
  size_t base = (size_t)blockIdx.x * D_;
  int d = threadIdx.x;
  float tv = x32[base + d];
  float sv = x32[base + (size_t)NT_ * D_ + d];
  float gsum = block_sum256(tv * gw[d], red) + gb[0];
  float gate = 1.0f / (1.0f + expf(-gsum));
  featbf[base + d] = f2bf(gate * tv + (1.0f - gate) * sv);
}

// ---------------------------------------------------------------- split-K reduce + bias + rescale
__global__ __launch_bounds__(256) void final_kernel(const float* __restrict__ part,
    const float* __restrict__ pb, const float* __restrict__ stdb,
    const float* __restrict__ meanb, float* __restrict__ y) {
  int i = blockIdx.x * 256 + threadIdx.x;         // 516096
  float acc = 0.f;
  #pragma unroll
  for (int z = 0; z < PZ_; ++z) acc += part[(size_t)z * 516096 + i];
  int b = i / 2016;
  int col = i - b * 2016;
  int m = col / H_;
  float sc = stdb[b * M_ + m] + 1e-5f;
  y[i] = (acc + pb[col]) * sc + meanb[b * M_ + m];
}

// ---------------------------------------------------------------- launch
extern "C" void kernel_launch(void* const* d_in, const int* in_sizes, int n_in,
                              void* d_out, int out_size, void* d_ws, size_t ws_size,
                              hipStream_t stream) {
  const float* x      = (const float*)d_in[0];
  const float* conv_w = (const float*)d_in[1];
  const float* conv_b = (const float*)d_in[2];
  const float* tP[16];
  const float* sP[16];
  for (int i = 0; i < 16; ++i) tP[i] = (const float*)d_in[3 + i];
  for (int i = 0; i < 16; ++i) sP[i] = (const float*)d_in[19 + i];
  const float* gate_w = (const float*)d_in[35];
  const float* gate_b = (const float*)d_in[36];
  const float* proj_w = (const float*)d_in[37];
  const float* proj_b = (const float*)d_in[38];
  float* out = (float*)d_out;

  // ---- workspace (floats): total 27,646,480 f = 110.6 MB
  float* ws    = (float*)d_ws;
  float* x32   = ws;                               // 8,257,536 (2 towers x NT x D)
  unsigned short* wb = (unsigned short*)(x32 + 8257536);  // 5,201,920 shorts
  float* meanb = x32 + 8257536 + 2600960;          // 5,376
  float* stdb  = meanb + 5376;                     // 5,376
  float* R1    = stdb + 5376 + 16;                 // 8,388,608
  float* R2    = R1 + 8388608;                     // 8,388,608

  unsigned short* im2colB = (unsigned short*)R1;           // pre-loop
  unsigned short* Zcat    = (unsigned short*)R1;           // dft -> H1
  unsigned short* Ycat1   = (unsigned short*)(R1 + 4194304); // H1 -> H2
  unsigned short* ptb     = (unsigned short*)(R1 + 4194304); // irfft -> Gp
  unsigned short* gp      = (unsigned short*)R1;           // Gp -> Tw
  unsigned short* featbf  = (unsigned short*)R1;           // post-loop

  float* xn     = R2;                              // pre-loop
  float* g0buf  = R2;                              // conv out (pre-loop)
  float* Ycat2f = R2;                              // H2 -> irfft
  unsigned short* hidB = (unsigned short*)R2;      // Ge -> Gp
  float* outb   = R2;                              // Tw -> ln
  float* part   = R2;                              // proj partials (PZ_ x 516096)

  unsigned short* convW = wb;                      // 256*352
  unsigned short* sets  = wb + 90112;              // 6 * (Gew 131072 + Gpw 131072 + Tw 65536)
  unsigned short* catW  = wb + 90112 + 1966080;    // 12 * 262144

  // ---- weight prep
  CvtArgs ca; int blk0 = 0, ne = 0;
  auto add_ent = [&](const float* s, unsigned short* d, int rows, int scol, int dcol) {
    ca.e[ne].src = s; ca.e[ne].dst = d; ca.e[ne].rows = rows;
    ca.e[ne].scol = scol; ca.e[ne].dcol = dcol; ca.e[ne].blk0 = blk0;
    blk0 += (rows * dcol + 255) / 256; ++ne;
  };
  add_ent(conv_w, convW, 256, 336, 352);
  for (int tw = 0; tw < 2; ++tw) {
    const float** Pp = tw ? (const float**)sP : (const float**)tP;
    for (int l = 0; l < 3; ++l) {
      unsigned short* sb = sets + (size_t)(tw * 3 + l) * 327680;
      add_ent(Pp[2] + (size_t)l * 131072, sb,          512, 256, 256);  // Gew
      add_ent(Pp[4] + (size_t)l * 131072, sb + 131072, 256, 512, 512);  // Gpw
      add_ent(Pp[0] + (size_t)l * 65536,  sb + 262144, 256, 256, 256);  // Tw
    }
  }
  ca.nent = ne;
  wprep_kernel<<<blk0, 256, 0, stream>>>(ca);

  CatArgs cat;
  for (int tw = 0; tw < 2; ++tw) {
    const float** Pp = tw ? (const float**)sP : (const float**)tP;
    for (int l = 0; l < 3; ++l) {
      int e0 = (tw * 3 + l) * 2;
      cat.wr[e0]     = Pp[6]  + (size_t)l * 65536;   // H1Wr
      cat.wi[e0]     = Pp[7]  + (size_t)l * 65536;   // H1Wi
      cat.wr[e0 + 1] = Pp[10] + (size_t)l * 65536;   // H2Wr
      cat.wi[e0 + 1] = Pp[11] + (size_t)l * 65536;   // H2Wi
    }
  }
  wcat_kernel<<<12 * 1024, 256, 0, stream>>>(cat, catW);

  // ---- stem
  norm_kernel<<<B_ * M_, 256, 0, stream>>>(x, xn, meanb, stdb);
  im2col_kernel<<<NT_, 256, 0, stream>>>(xn, im2colB);
  mm_kernel<0, 0, 0, 11, 0, 0, 0, 0, 0><<<dim3(2, 126), 256, 0, stream>>>(
      im2colB, convW, convW, nullptr, conv_b, conv_b, nullptr, g0buf,
      KCP_, 256, 0, 1 << 30, 0);
  add_pe_kernel<<<NT_, 256, 0, stream>>>(g0buf, x32);

  // ---- layers (both towers batched; freq branch first, then MLP with x pt fuse)
  for (int l = 0; l < 3; ++l) {
    unsigned short* st0 = sets + (size_t)l * 327680;
    unsigned short* st1 = sets + (size_t)(3 + l) * 327680;
    unsigned short* c1t0 = catW + (size_t)((0 + l) * 2) * 262144;
    unsigned short* c2t0 = c1t0 + 262144;
    unsigned short* c1t1 = catW + (size_t)((3 + l) * 2) * 262144;
    unsigned short* c2t1 = c1t1 + 262144;

    dft_kernel<<<2 * B_, 256, 0, stream>>>(x32, Zcat);
    mm_kernel<0, 1, 1, 16, 0, 0, 1, 0, 0><<<dim3(4, 128), 256, 0, stream>>>(
        Zcat, c1t0, c1t1, nullptr, tP[9] + (size_t)l * D_, sP[9] + (size_t)l * D_,
        nullptr, Ycat1, 512, 512, 0, 64, 0);
    mm_kernel<0, 0, 1, 16, 0, 0, 0, 0, 0><<<dim3(4, 128), 256, 0, stream>>>(
        Ycat1, c2t0, c2t1, nullptr, tP[13] + (size_t)l * D_, sP[13] + (size_t)l * D_,
        nullptr, Ycat2f, 512, 512, 0, 64, 0);
    irfft_kernel<<<dim3(7, 2 * B_), 256, 0, stream>>>(Ycat2f, ptb);
    mm_kernel<1, 1, 0, 8, 1, 0, 0, 0, 0><<<dim3(4, 252), 256, 0, stream>>>(
        x32, st0, st1, nullptr, tP[3] + (size_t)l * HID_, sP[3] + (size_t)l * HID_,
        nullptr, hidB, 256, 512, 0, 126, 0);
    mm_kernel<0, 1, 0, 16, 0, 0, 0, 1, 0><<<dim3(2, 252), 256, 0, stream>>>(
        hidB, st0 + 131072, st1 + 131072, nullptr,
        tP[5] + (size_t)l * D_, sP[5] + (size_t)l * D_, ptb, gp, 512, 256, 0, 126, 0);
    mm_kernel<0, 0, 0, 8, 0, 0, 0, 0, 0><<<dim3(2, 252), 256, 0, stream>>>(
        gp, st0 + 262144, st1 + 262144, nullptr,
        tP[1] + (size_t)l * D_, sP[1] + (size_t)l * D_, nullptr, outb, 256, 256, 0, 126, 0);
    ln_kernel<<<2 * NT_, 256, 0, stream>>>(outb, x32,
        tP[14] + (size_t)l * D_, tP[15] + (size_t)l * D_,
        sP[14] + (size_t)l * D_, sP[15] + (size_t)l * D_, NT_);
  }

  // ---- head
  gate_feat_kernel<<<NT_, 256, 0, stream>>>(x32, gate_w, gate_b, featbf);
  mm_kernel<0, 0, 2, 0, 0, 1, 0, 0, 1><<<dim3(16, 2, PZ_), 256, 0, stream>>>(
      featbf, nullptr, nullptr, proj_w, nullptr, nullptr, nullptr, part,
      NT_, 2016, 504 / PZ_, 1 << 30, 256);
  final_kernel<<<2016, 256, 0, stream>>>(part, proj_b, stdb, meanb, out);
}

// Round 4
// 1066.727 us; speedup vs baseline: 3.8505x; 1.2314x over previous
//
#include <hip/hip_runtime.h>
#include <cstddef>
#include <cstdint>

#define B_    256
#define M_    21
#define L_    512
#define D_    256
#define T_    63
#define F_    32
#define NT_   16128   // B_*T_
#define HID_  512
#define KCP_  352     // M_*P_=336 padded to 32
#define H_    96
#define LAM_  0.01f
#define PZ_   12      // proj split-K factor

typedef __attribute__((ext_vector_type(8))) short short8;
typedef __attribute__((ext_vector_type(4))) float f32x4;
typedef unsigned int u32;
typedef const u32 __attribute__((address_space(1)))* gas1_t;
typedef u32 __attribute__((address_space(3)))* las3_t;

__device__ __forceinline__ void async_copy16(const void* g, void* l) {
  __builtin_amdgcn_global_load_lds((gas1_t)g, (las3_t)(uintptr_t)l, 16, 0, 0);
}
__device__ __forceinline__ unsigned short f2bf(float x) {   // RNE
  unsigned u = __float_as_uint(x);
  return (unsigned short)((u + 0x7FFF + ((u >> 16) & 1)) >> 16);
}
__device__ __forceinline__ float bf2f(unsigned short u) {
  return __uint_as_float(((unsigned)u) << 16);
}
__device__ __forceinline__ float gelu_exact(float v) {
  return 0.5f * v * (1.0f + erff(v * 0.70710678118654752f));
}
__device__ __forceinline__ float block_sum256(float v, float* red4) {
  #pragma unroll
  for (int off = 32; off > 0; off >>= 1) v += __shfl_down(v, off, 64);
  if ((threadIdx.x & 63) == 0) red4[threadIdx.x >> 6] = v;
  __syncthreads();
  float r = red4[0] + red4[1] + red4[2] + red4[3];
  __syncthreads();
  return r;
}
__device__ __forceinline__ float wave_sum(float v) {
  #pragma unroll
  for (int off = 1; off < 64; off <<= 1) v += __shfl_xor(v, off, 64);
  return v;
}

// ---------------------------------------------------------------- weight prep
struct CvtEnt { const float* src; unsigned short* dst; int rows, scol, dcol, blk0; };
struct CvtArgs { CvtEnt e[19]; int nent; };
__global__ __launch_bounds__(256) void wprep_kernel(CvtArgs a) {
  int blk = blockIdx.x, e = 0;
  while (e + 1 < a.nent && a.e[e + 1].blk0 <= blk) ++e;
  CvtEnt en = a.e[e];
  int idx = (blk - en.blk0) * 256 + threadIdx.x;
  int total = en.rows * en.dcol;
  if (idx >= total) return;
  int r = idx / en.dcol, c = idx - r * en.dcol;
  float v = (c < en.scol) ? en.src[(size_t)r * en.scol + c] : 0.f;
  en.dst[idx] = f2bf(v);
}

// interleaved cat weight: row 2c+p, col 2d+q
// p=0 (yr): q=0 -> Wr[c,d], q=1 -> -Wi[c,d]
// p=1 (yi): q=0 -> Wi[c,d], q=1 ->  Wr[c,d]
struct CatArgs { const float* wr[12]; const float* wi[12]; };
__global__ __launch_bounds__(256) void wcat_kernel(CatArgs a, unsigned short* dst) {
  int e = blockIdx.x >> 10;
  int idx = ((blockIdx.x & 1023) << 8) + threadIdx.x;
  int r = idx >> 9, c = idx & 511;
  int cp = r >> 1, p = r & 1, d = c >> 1, q = c & 1;
  const float* wr = a.wr[e];
  const float* wi = a.wi[e];
  float v;
  if (p == 0) v = (q == 0) ? wr[cp * 256 + d] : -wi[cp * 256 + d];
  else        v = (q == 0) ? wi[cp * 256 + d] :  wr[cp * 256 + d];
  dst[(size_t)e * 262144 + idx] = f2bf(v);
}

// ---------------------------------------------------------------- MFMA GEMM
// C = A @ W^T (+bias). 128x128 tile, 4 waves, 4x4 16x16x32-bf16 MFMA each.
// Tower select: blockIdx.y >= yhalf -> W1/b1.
// BIASM: 0 normal, 1 interleaved clin (odd col: 2*bi[col>>1]), 2 none(+col guard).
// CVTA: stage A from fp32. CVTW: stage W from fp32. SHRINK: softshrink via shfl_xor.
// MULPT: epilogue *= pt[row,col] (bf16). SPLITK: partials at z*prow*Dout.
template <int ACT, int OUTBF, int BIASM, int KSTEPS, int CVTA, int CVTW,
          int SHRINK, int MULPT, int SPLITK>
__global__ __launch_bounds__(256) void mm_kernel(
    const void* __restrict__ Av,
    const unsigned short* __restrict__ W0, const unsigned short* __restrict__ W1,
    const float* __restrict__ Wf,
    const float* __restrict__ b0, const float* __restrict__ b1,
    const unsigned short* __restrict__ ptb,
    void* __restrict__ Cv,
    const int K, const int Dout, const int ksteps_rt, const int yhalf, const int prow) {
  __shared__ __align__(16) unsigned short As[128 * 32];
  __shared__ __align__(16) unsigned short Bs[128 * 32];
  const int ksteps = KSTEPS ? KSTEPS : ksteps_rt;
  const int tid = threadIdx.x, w = tid >> 6, lane = tid & 63;
  const int quad = lane >> 4, r16 = lane & 15;
  const int kst = SPLITK ? (int)blockIdx.z * ksteps * 32 : 0;
  const int tower = ((int)blockIdx.y >= yhalf) ? 1 : 0;
  const unsigned short* Wb = tower ? W1 : W0;
  const float* bias = tower ? b1 : b0;

  const unsigned short* Ab = (const unsigned short*)Av;
  const float* Af = (const float*)Av;
  const unsigned short* gA = nullptr;
  unsigned short* lA = As + (w * 32) * 32;
  if (!CVTA) gA = Ab + (size_t)(blockIdx.y * 128 + w * 32 + (lane >> 2)) * K
                     + kst + (lane & 3) * 8;
  const unsigned short* gB = nullptr;
  unsigned short* lB = Bs + (w * 32) * 32;
  if (!CVTW) gB = Wb + (size_t)(blockIdx.x * 128 + w * 32 + (lane >> 2)) * K
                     + kst + (lane & 3) * 8;

  f32x4 acc[4][4];
  #pragma unroll
  for (int i = 0; i < 4; ++i)
    #pragma unroll
    for (int j = 0; j < 4; ++j)
      #pragma unroll
      for (int r = 0; r < 4; ++r) acc[i][j][r] = 0.f;

  for (int ks = 0; ks < ksteps; ++ks) {
    if (!CVTA) {
      async_copy16(gA, lA);
      async_copy16(gA + (size_t)16 * K, lA + 16 * 32);
      gA += 32;
    } else {
      int rowA = tid >> 1, halfk = (tid & 1) << 4;
      const float* asrc = Af + (size_t)((int)blockIdx.y * 128 + rowA) * K + ks * 32 + halfk;
      union { unsigned short u[16]; uint4 q[2]; } pk;
      #pragma unroll
      for (int n = 0; n < 16; n += 4) {
        float4 v = *reinterpret_cast<const float4*>(asrc + n);
        pk.u[n] = f2bf(v.x); pk.u[n + 1] = f2bf(v.y);
        pk.u[n + 2] = f2bf(v.z); pk.u[n + 3] = f2bf(v.w);
      }
      uint4* ad = reinterpret_cast<uint4*>(As + rowA * 32 + halfk);
      ad[0] = pk.q[0]; ad[1] = pk.q[1];
    }
    if (!CVTW) {
      async_copy16(gB, lB);
      async_copy16(gB + (size_t)16 * K, lB + 16 * 32);
      gB += 32;
    } else {
      int rowW = tid >> 1, halfk = (tid & 1) << 4;
      int wrow = blockIdx.x * 128 + rowW;
      if (wrow >= Dout) wrow = Dout - 1;
      const float* wsrc = Wf + (size_t)wrow * K + kst + ks * 32 + halfk;
      union { unsigned short u[16]; uint4 q[2]; } pk;
      #pragma unroll
      for (int n = 0; n < 16; n += 4) {
        float4 v = *reinterpret_cast<const float4*>(wsrc + n);
        pk.u[n] = f2bf(v.x); pk.u[n + 1] = f2bf(v.y);
        pk.u[n + 2] = f2bf(v.z); pk.u[n + 3] = f2bf(v.w);
      }
      uint4* bd = reinterpret_cast<uint4*>(Bs + rowW * 32 + halfk);
      bd[0] = pk.q[0]; bd[1] = pk.q[1];
    }
    __syncthreads();
    const unsigned short* pa = As + (64 * (w >> 1) + r16) * 32 + quad * 8;
    const unsigned short* pb = Bs + (64 * (w & 1) + r16) * 32 + quad * 8;
    short8 af[4], bfv[4];
    #pragma unroll
    for (int i = 0; i < 4; ++i) af[i] = *reinterpret_cast<const short8*>(pa + i * 512);
    #pragma unroll
    for (int j = 0; j < 4; ++j) bfv[j] = *reinterpret_cast<const short8*>(pb + j * 512);
    #pragma unroll
    for (int i = 0; i < 4; ++i)
      #pragma unroll
      for (int j = 0; j < 4; ++j)
        acc[i][j] = __builtin_amdgcn_mfma_f32_16x16x32_bf16(af[i], bfv[j], acc[i][j], 0, 0, 0);
    __syncthreads();
  }

  float* Cf = (float*)Cv;
  unsigned short* Cb = (unsigned short*)Cv;
  if (SPLITK) Cf += (size_t)blockIdx.z * prow * Dout;
  const int colb = blockIdx.x * 128 + 64 * (w & 1) + r16;
  const int rowb = blockIdx.y * 128 + 64 * (w >> 1) + quad * 4;
  #pragma unroll
  for (int j = 0; j < 4; ++j) {
    int col = colb + 16 * j;
    float bv = 0.f;
    if (BIASM == 0) bv = bias[col];
    else if (BIASM == 1) bv = (col & 1) ? 2.0f * bias[col >> 1] : 0.f;
    bool colok = (BIASM != 2) || (col < Dout);
    #pragma unroll
    for (int i = 0; i < 4; ++i) {
      #pragma unroll
      for (int r = 0; r < 4; ++r) {
        int row = rowb + 16 * i + r;
        float v = acc[i][j][r] + bv;
        if (ACT == 1) v = gelu_exact(v);
        if (SHRINK) {
          float o = __shfl_xor(v, 1, 64);
          float mag = sqrtf(v * v + o * o);
          float s = (mag > LAM_) ? (mag - LAM_) / (mag + 1e-8f) : 0.f;
          v *= s;
        }
        if (MULPT) v *= bf2f(ptb[(size_t)row * Dout + col]);
        if (colok) {
          if (OUTBF) Cb[(size_t)row * Dout + col] = f2bf(v);
          else       Cf[(size_t)row * Dout + col] = v;
        }
      }
    }
  }
}

// ---------------------------------------------------------------- norm
__global__ __launch_bounds__(256) void norm_kernel(const float* __restrict__ x,
    float* __restrict__ xn, float* __restrict__ meanb, float* __restrict__ stdb) {
  __shared__ float red[4];
  int bm = blockIdx.x;
  const float* xr = x + (size_t)bm * L_;
  float v0 = xr[threadIdx.x], v1 = xr[threadIdx.x + 256];
  float mu = block_sum256(v0 + v1, red) * (1.0f / L_);
  float d0 = v0 - mu, d1 = v1 - mu;
  float sd = sqrtf(block_sum256(d0 * d0 + d1 * d1, red) * (1.0f / L_));
  float inv = 1.0f / (sd + 1e-5f);
  float* xo = xn + (size_t)bm * L_;
  xo[threadIdx.x] = d0 * inv;
  xo[threadIdx.x + 256] = d1 * inv;
  if (threadIdx.x == 0) { meanb[bm] = mu; stdb[bm] = sd; }
}

// ---------------------------------------------------------------- im2col -> bf16 K=352
__global__ __launch_bounds__(256) void im2col_kernel(const float* __restrict__ xn,
                                                     unsigned short* __restrict__ im) {
  int row = blockIdx.x;
  int b = row / T_, t = row - b * T_;
  const float* xb = xn + (size_t)b * M_ * L_ + t * 8;
  unsigned short* o = im + (size_t)row * KCP_;
  for (int i = threadIdx.x; i < KCP_; i += 256) {
    float v = 0.f;
    if (i < 336) { int m = i >> 4, p = i & 15; v = xb[m * L_ + p]; }
    o[i] = f2bf(v);
  }
}

// ---------------------------------------------------------------- pos-enc + dup into both towers
__global__ __launch_bounds__(256) void add_pe_kernel(const float* __restrict__ g0,
                                                     float* __restrict__ x32) {
  int row = blockIdx.x, d = threadIdx.x;
  int t = row % T_;
  size_t idx = (size_t)row * D_ + d;
  float freq = expf((float)(d & ~1) * (-9.210340371976184f / 256.0f));
  float ang = (float)t * freq;
  float pe = (d & 1) ? cosf(ang) : sinf(ang);
  float h = g0[idx] + pe;
  x32[idx] = h;
  x32[idx + (size_t)NT_ * D_] = h;
}

// ---------------------------------------------------------------- DFT along T (rfft)
// one block per bt. Expanded LDS trig table [t][f] = (cos, -sin); f-loop unrolled
// with immediate ds_read_b64 offsets; 64 accumulator VGPRs (re/im x 32 f).
__global__ __launch_bounds__(256) void dft_kernel(const float* __restrict__ X,
                                                  unsigned short* __restrict__ Zcat) {
  __shared__ float2 tw[T_ * F_];     // 15.75 KB
  int bt = blockIdx.x, d = threadIdx.x;
  for (int i = threadIdx.x; i < T_ * F_; i += 256) {
    int t = i >> 5, f = i & 31;
    int k = (f * t) % T_;
    float sn, cs;
    sincosf((6.283185307179586f / 63.0f) * (float)k, &sn, &cs);
    tw[i] = make_float2(cs, -sn);
  }
  __syncthreads();
  const float* xb = X + (size_t)bt * T_ * D_ + d;
  float ar[F_], ai[F_];
  #pragma unroll
  for (int f = 0; f < F_; ++f) { ar[f] = 0.f; ai[f] = 0.f; }
  for (int t = 0; t < T_; ++t) {
    float v = xb[(size_t)t * D_];
    const float2* w = &tw[t * F_];
    #pragma unroll
    for (int f = 0; f < F_; ++f) {
      float2 c = w[f];
      ar[f] = fmaf(v, c.x, ar[f]);
      ai[f] = fmaf(v, c.y, ai[f]);
    }
  }
  u32* z = reinterpret_cast<u32*>(Zcat + (size_t)bt * F_ * 512);
  #pragma unroll
  for (int f = 0; f < F_; ++f)
    z[f * 256 + d] = (u32)f2bf(ar[f]) | ((u32)f2bf(ai[f]) << 16);
}

// ---------------------------------------------------------------- irfft(n=63) -> pt bf16
// one block per bt; Y column in registers (read once); table [t][f-1] with
// (2/63*cos, -2/63*sin) folded; two accumulator chains per t.
__global__ __launch_bounds__(256) void irfft_kernel(const float* __restrict__ Y,
                                                    unsigned short* __restrict__ ptb) {
  __shared__ float2 tw[T_ * 31];     // 15.26 KB
  int bt = blockIdx.x, d = threadIdx.x;
  for (int i = threadIdx.x; i < T_ * 31; i += 256) {
    int t = i / 31, f = i - t * 31 + 1;
    int k = (f * t) % T_;
    float sn, cs;
    sincosf((6.283185307179586f / 63.0f) * (float)k, &sn, &cs);
    tw[i] = make_float2(cs * (2.0f / 63.0f), -sn * (2.0f / 63.0f));
  }
  __syncthreads();
  const float* yb = Y + (size_t)bt * F_ * 512 + 2 * d;
  float y0 = yb[0] * (1.0f / 63.0f);   // f=0: Re only (odd-n irfft ignores Im(X0))
  float yr[31], yi[31];
  #pragma unroll
  for (int f = 1; f < F_; ++f) {
    float2 p = *reinterpret_cast<const float2*>(yb + (size_t)f * 512);
    yr[f - 1] = p.x;
    yi[f - 1] = p.y;
  }
  unsigned short* po = ptb + (size_t)bt * T_ * D_ + d;
  for (int t = 0; t < T_; ++t) {
    const float2* w = &tw[t * 31];
    float acc0 = y0, acc1 = 0.f;
    #pragma unroll
    for (int f = 0; f < 31; f += 2) {
      float2 c = w[f];
      acc0 = fmaf(yr[f], c.x, fmaf(yi[f], c.y, acc0));
      if (f + 1 < 31) {
        float2 c1 = w[f + 1];
        acc1 = fmaf(yr[f + 1], c1.x, fmaf(yi[f + 1], c1.y, acc1));
      }
    }
    po[(size_t)t * D_] = f2bf(acc0 + acc1);
  }
}

// ---------------------------------------------------------------- add + layernorm (wave per row, in-place x32)
__global__ __launch_bounds__(256) void ln_kernel(const float* __restrict__ outb,
    float* __restrict__ x, const float* __restrict__ g0, const float* __restrict__ b0,
    const float* __restrict__ g1, const float* __restrict__ b1, int yhalf) {
  int row = blockIdx.x * 4 + (threadIdx.x >> 6);
  int lane = threadIdx.x & 63;
  const float* g = (row >= yhalf) ? g1 : g0;
  const float* b = (row >= yhalf) ? b1 : b0;
  size_t base = (size_t)row * D_ + lane * 4;
  float4 ov = *reinterpret_cast<const float4*>(outb + base);
  float4 xv = *reinterpret_cast<const float4*>(x + base);
  float v0 = ov.x + xv.x, v1 = ov.y + xv.y, v2 = ov.z + xv.z, v3 = ov.w + xv.w;
  float mu = wave_sum(v0 + v1 + v2 + v3) * (1.0f / D_);
  v0 -= mu; v1 -= mu; v2 -= mu; v3 -= mu;
  float var = wave_sum(v0 * v0 + v1 * v1 + v2 * v2 + v3 * v3) * (1.0f / D_);
  float is = rsqrtf(var + 1e-5f);
  float4 gv = *reinterpret_cast<const float4*>(g + lane * 4);
  float4 bv = *reinterpret_cast<const float4*>(b + lane * 4);
  float4 o;
  o.x = v0 * is * gv.x + bv.x;
  o.y = v1 * is * gv.y + bv.y;
  o.z = v2 * is * gv.z + bv.z;
  o.w = v3 * is * gv.w + bv.w;
  *reinterpret_cast<float4*>(x + base) = o;
}

// ---------------------------------------------------------------- gate + blend -> bf16 feat
__global__ __launch_bounds__(256) void gate_feat_kernel(const float* __restrict__ x32,
    const float* __restrict__ gw, const float* __restrict__ gb,
    unsigned short* __restrict__ featbf) {
  __shared__ float red[4];
  size_t base = (size_t)blockIdx.x * D_;
  int d = threadIdx.x;
  float tv = x32[base + d];
  float sv = x32[base + (size_t)NT_ * D_ + d];
  float gsum = block_sum256(tv * gw[d], red) + gb[0];
  float gate = 1.0f / (1.0f + expf(-gsum));
  featbf[base + d] = f2bf(gate * tv + (1.0f - gate) * sv);
}

// ---------------------------------------------------------------- split-K reduce + bias + rescale
__global__ __launch_bounds__(256) void final_kernel(const float* __restrict__ part,
    const float* __restrict__ pb, const float* __restrict__ stdb,
    const float* __restrict__ meanb, float* __restrict__ y) {
  int i = blockIdx.x * 256 + threadIdx.x;         // 516096
  float acc = 0.f;
  #pragma unroll
  for (int z = 0; z < PZ_; ++z) acc += part[(size_t)z * 516096 + i];
  int b = i / 2016;
  int col = i - b * 2016;
  int m = col / H_;
  float sc = stdb[b * M_ + m] + 1e-5f;
  y[i] = (acc + pb[col]) * sc + meanb[b * M_ + m];
}

// ---------------------------------------------------------------- launch
extern "C" void kernel_launch(void* const* d_in, const int* in_sizes, int n_in,
                              void* d_out, int out_size, void* d_ws, size_t ws_size,
                              hipStream_t stream) {
  const float* x      = (const float*)d_in[0];
  const float* conv_w = (const float*)d_in[1];
  const float* conv_b = (const float*)d_in[2];
  const float* tP[16];
  const float* sP[16];
  for (int i = 0; i < 16; ++i) tP[i] = (const float*)d_in[3 + i];
  for (int i = 0; i < 16; ++i) sP[i] = (const float*)d_in[19 + i];
  const float* gate_w = (const float*)d_in[35];
  const float* gate_b = (const float*)d_in[36];
  const float* proj_w = (const float*)d_in[37];
  const float* proj_b = (const float*)d_in[38];
  float* out = (float*)d_out;

  // ---- workspace (floats): total 27,646,480 f = 110.6 MB
  float* ws    = (float*)d_ws;
  float* x32   = ws;                               // 8,257,536 (2 towers x NT x D)
  unsigned short* wb = (unsigned short*)(x32 + 8257536);  // 5,201,920 shorts
  float* meanb = x32 + 8257536 + 2600960;          // 5,376
  float* stdb  = meanb + 5376;                     // 5,376
  float* R1    = stdb + 5376 + 16;                 // 8,388,608
  float* R2    = R1 + 8388608;                     // 8,388,608

  unsigned short* im2colB = (unsigned short*)R1;           // pre-loop
  unsigned short* Zcat    = (unsigned short*)R1;           // dft -> H1
  unsigned short* Ycat1   = (unsigned short*)(R1 + 4194304); // H1 -> H2
  unsigned short* ptb     = (unsigned short*)(R1 + 4194304); // irfft -> Gp
  unsigned short* gp      = (unsigned short*)R1;           // Gp -> Tw
  unsigned short* featbf  = (unsigned short*)R1;           // post-loop

  float* xn     = R2;                              // pre-loop
  float* g0buf  = R2;                              // conv out (pre-loop)
  float* Ycat2f = R2;                              // H2 -> irfft
  unsigned short* hidB = (unsigned short*)R2;      // Ge -> Gp
  float* outb   = R2;                              // Tw -> ln
  float* part   = R2;                              // proj partials (PZ_ x 516096)

  unsigned short* convW = wb;                      // 256*352
  unsigned short* sets  = wb + 90112;              // 6 * (Gew 131072 + Gpw 131072 + Tw 65536)
  unsigned short* catW  = wb + 90112 + 1966080;    // 12 * 262144

  // ---- weight prep
  CvtArgs ca; int blk0 = 0, ne = 0;
  auto add_ent = [&](const float* s, unsigned short* d, int rows, int scol, int dcol) {
    ca.e[ne].src = s; ca.e[ne].dst = d; ca.e[ne].rows = rows;
    ca.e[ne].scol = scol; ca.e[ne].dcol = dcol; ca.e[ne].blk0 = blk0;
    blk0 += (rows * dcol + 255) / 256; ++ne;
  };
  add_ent(conv_w, convW, 256, 336, 352);
  for (int tw = 0; tw < 2; ++tw) {
    const float** Pp = tw ? (const float**)sP : (const float**)tP;
    for (int l = 0; l < 3; ++l) {
      unsigned short* sb = sets + (size_t)(tw * 3 + l) * 327680;
      add_ent(Pp[2] + (size_t)l * 131072, sb,          512, 256, 256);  // Gew
      add_ent(Pp[4] + (size_t)l * 131072, sb + 131072, 256, 512, 512);  // Gpw
      add_ent(Pp[0] + (size_t)l * 65536,  sb + 262144, 256, 256, 256);  // Tw
    }
  }
  ca.nent = ne;
  wprep_kernel<<<blk0, 256, 0, stream>>>(ca);

  CatArgs cat;
  for (int tw = 0; tw < 2; ++tw) {
    const float** Pp = tw ? (const float**)sP : (const float**)tP;
    for (int l = 0; l < 3; ++l) {
      int e0 = (tw * 3 + l) * 2;
      cat.wr[e0]     = Pp[6]  + (size_t)l * 65536;   // H1Wr
      cat.wi[e0]     = Pp[7]  + (size_t)l * 65536;   // H1Wi
      cat.wr[e0 + 1] = Pp[10] + (size_t)l * 65536;   // H2Wr
      cat.wi[e0 + 1] = Pp[11] + (size_t)l * 65536;   // H2Wi
    }
  }
  wcat_kernel<<<12 * 1024, 256, 0, stream>>>(cat, catW);

  // ---- stem
  norm_kernel<<<B_ * M_, 256, 0, stream>>>(x, xn, meanb, stdb);
  im2col_kernel<<<NT_, 256, 0, stream>>>(xn, im2colB);
  mm_kernel<0, 0, 0, 11, 0, 0, 0, 0, 0><<<dim3(2, 126), 256, 0, stream>>>(
      im2colB, convW, convW, nullptr, conv_b, conv_b, nullptr, g0buf,
      KCP_, 256, 0, 1 << 30, 0);
  add_pe_kernel<<<NT_, 256, 0, stream>>>(g0buf, x32);

  // ---- layers (both towers batched; freq branch first, then MLP with x pt fuse)
  for (int l = 0; l < 3; ++l) {
    unsigned short* st0 = sets + (size_t)l * 327680;
    unsigned short* st1 = sets + (size_t)(3 + l) * 327680;
    unsigned short* c1t0 = catW + (size_t)((0 + l) * 2) * 262144;
    unsigned short* c2t0 = c1t0 + 262144;
    unsigned short* c1t1 = catW + (size_t)((3 + l) * 2) * 262144;
    unsigned short* c2t1 = c1t1 + 262144;

    dft_kernel<<<2 * B_, 256, 0, stream>>>(x32, Zcat);
    mm_kernel<0, 1, 1, 16, 0, 0, 1, 0, 0><<<dim3(4, 128), 256, 0, stream>>>(
        Zcat, c1t0, c1t1, nullptr, tP[9] + (size_t)l * D_, sP[9] + (size_t)l * D_,
        nullptr, Ycat1, 512, 512, 0, 64, 0);
    mm_kernel<0, 0, 1, 16, 0, 0, 0, 0, 0><<<dim3(4, 128), 256, 0, stream>>>(
        Ycat1, c2t0, c2t1, nullptr, tP[13] + (size_t)l * D_, sP[13] + (size_t)l * D_,
        nullptr, Ycat2f, 512, 512, 0, 64, 0);
    irfft_kernel<<<2 * B_, 256, 0, stream>>>(Ycat2f, ptb);
    mm_kernel<1, 1, 0, 8, 1, 0, 0, 0, 0><<<dim3(4, 252), 256, 0, stream>>>(
        x32, st0, st1, nullptr, tP[3] + (size_t)l * HID_, sP[3] + (size_t)l * HID_,
        nullptr, hidB, 256, 512, 0, 126, 0);
    mm_kernel<0, 1, 0, 16, 0, 0, 0, 1, 0><<<dim3(2, 252), 256, 0, stream>>>(
        hidB, st0 + 131072, st1 + 131072, nullptr,
        tP[5] + (size_t)l * D_, sP[5] + (size_t)l * D_, ptb, gp, 512, 256, 0, 126, 0);
    mm_kernel<0, 0, 0, 8, 0, 0, 0, 0, 0><<<dim3(2, 252), 256, 0, stream>>>(
        gp, st0 + 262144, st1 + 262144, nullptr,
        tP[1] + (size_t)l * D_, sP[1] + (size_t)l * D_, nullptr, outb, 256, 256, 0, 126, 0);
    ln_kernel<<<2 * NT_ / 4, 256, 0, stream>>>(outb, x32,
        tP[14] + (size_t)l * D_, tP[15] + (size_t)l * D_,
        sP[14] + (size_t)l * D_, sP[15] + (size_t)l * D_, NT_);
  }

  // ---- head
  gate_feat_kernel<<<NT_, 256, 0, stream>>>(x32, gate_w, gate_b, featbf);
  mm_kernel<0, 0, 2, 0, 0, 1, 0, 0, 1><<<dim3(16, 2, PZ_), 256, 0, stream>>>(
      featbf, nullptr, nullptr, proj_w, nullptr, nullptr, nullptr, part,
      NT_, 2016, 504 / PZ_, 1 << 30, 256);
  final_kernel<<<2016, 256, 0, stream>>>(part, proj_b, stdb, meanb, out);
}

// Round 5
// 1022.441 us; speedup vs baseline: 4.0173x; 1.0433x over previous
//
#include <hip/hip_runtime.h>
#include <cstddef>
#include <cstdint>

#define B_    256
#define M_    21
#define L_    512
#define D_    256
#define T_    63
#define F_    32
#define NT_   16128   // B_*T_
#define HID_  512
#define KCP_  352     // M_*P_=336 padded to 32
#define H_    96
#define LAM_  0.01f
#define PZ_   14      // proj split-K factor (504/14 = 36 k32-steps)

typedef __attribute__((ext_vector_type(8))) short short8;
typedef __attribute__((ext_vector_type(4))) float f32x4;
typedef unsigned int u32;
typedef const u32 __attribute__((address_space(1)))* gas1_t;
typedef u32 __attribute__((address_space(3)))* las3_t;

__device__ __forceinline__ void async_copy16(const void* g, void* l) {
  __builtin_amdgcn_global_load_lds((gas1_t)g, (las3_t)(uintptr_t)l, 16, 0, 0);
}
__device__ __forceinline__ unsigned short f2bf(float x) {   // RNE
  unsigned u = __float_as_uint(x);
  return (unsigned short)((u + 0x7FFF + ((u >> 16) & 1)) >> 16);
}
__device__ __forceinline__ float bf2f(unsigned short u) {
  return __uint_as_float(((unsigned)u) << 16);
}
__device__ __forceinline__ float gelu_exact(float v) {
  return 0.5f * v * (1.0f + erff(v * 0.70710678118654752f));
}
__device__ __forceinline__ float block_sum256(float v, float* red4) {
  #pragma unroll
  for (int off = 32; off > 0; off >>= 1) v += __shfl_down(v, off, 64);
  if ((threadIdx.x & 63) == 0) red4[threadIdx.x >> 6] = v;
  __syncthreads();
  float r = red4[0] + red4[1] + red4[2] + red4[3];
  __syncthreads();
  return r;
}
__device__ __forceinline__ float wave_sum(float v) {
  #pragma unroll
  for (int off = 1; off < 64; off <<= 1) v += __shfl_xor(v, off, 64);
  return v;
}

// ---------------------------------------------------------------- weight prep
struct CvtEnt { const float* src; unsigned short* dst; int rows, scol, dcol, blk0; };
struct CvtArgs { CvtEnt e[19]; int nent; };
__global__ __launch_bounds__(256) void wprep_kernel(CvtArgs a) {
  int blk = blockIdx.x, e = 0;
  while (e + 1 < a.nent && a.e[e + 1].blk0 <= blk) ++e;
  CvtEnt en = a.e[e];
  int idx = (blk - en.blk0) * 256 + threadIdx.x;
  int total = en.rows * en.dcol;
  if (idx >= total) return;
  int r = idx / en.dcol, c = idx - r * en.dcol;
  float v = (c < en.scol) ? en.src[(size_t)r * en.scol + c] : 0.f;
  en.dst[idx] = f2bf(v);
}

// interleaved cat weight: row 2c+p, col 2d+q
struct CatArgs { const float* wr[12]; const float* wi[12]; };
__global__ __launch_bounds__(256) void wcat_kernel(CatArgs a, unsigned short* dst) {
  int e = blockIdx.x >> 10;
  int idx = ((blockIdx.x & 1023) << 8) + threadIdx.x;
  int r = idx >> 9, c = idx & 511;
  int cp = r >> 1, p = r & 1, d = c >> 1, q = c & 1;
  const float* wr = a.wr[e];
  const float* wi = a.wi[e];
  float v;
  if (p == 0) v = (q == 0) ? wr[cp * 256 + d] : -wi[cp * 256 + d];
  else        v = (q == 0) ? wi[cp * 256 + d] :  wr[cp * 256 + d];
  dst[(size_t)e * 262144 + idx] = f2bf(v);
}

// ---------------------------------------------------------------- MFMA GEMM
// C = A @ W^T (+bias). 128x128 tile, 4 waves, 4x4 16x16x32-bf16 MFMA each.
// BK = 32 or 64; LDS organized as [BK/32 panels][128][32] so async lane*16
// contiguity and the 64B-row-stride frag-read pattern are preserved.
// BIASM: 0 normal, 1 interleaved clin (odd col: 2*bi[col>>1]), 2 none+col guard.
// CVTA/CVTW: sync-stage from fp32 (8 lanes/row -> 128B contiguous segments).
template <int ACT, int OUTBF, int BIASM, int KSTEPS, int CVTA, int CVTW,
          int SHRINK, int MULPT, int SPLITK, int BK>
__global__ __launch_bounds__(256) void mm_kernel(
    const void* __restrict__ Av,
    const unsigned short* __restrict__ W0, const unsigned short* __restrict__ W1,
    const float* __restrict__ Wf,
    const float* __restrict__ b0, const float* __restrict__ b1,
    const unsigned short* __restrict__ ptb,
    void* __restrict__ Cv,
    const int K, const int Dout, const int ksteps_rt, const int yhalf, const int prow) {
  constexpr int NP = BK / 32;
  __shared__ __align__(16) unsigned short As[NP * 128 * 32];
  __shared__ __align__(16) unsigned short Bs[NP * 128 * 32];
  const int ksteps = KSTEPS ? KSTEPS : ksteps_rt;
  const int tid = threadIdx.x, w = tid >> 6, lane = tid & 63;
  const int quad = lane >> 4, r16 = lane & 15;
  const int kst = SPLITK ? (int)blockIdx.z * ksteps * BK : 0;
  const int tower = ((int)blockIdx.y >= yhalf) ? 1 : 0;
  const unsigned short* Wb = tower ? W1 : W0;
  const float* bias = tower ? b1 : b0;

  const unsigned short* Ab = (const unsigned short*)Av;
  const float* Af = (const float*)Av;
  const unsigned short* gA = nullptr;
  unsigned short* lA = As + (w * 32) * 32;
  if (!CVTA) gA = Ab + (size_t)(blockIdx.y * 128 + w * 32 + (lane >> 2)) * K
                     + kst + (lane & 3) * 8;
  const unsigned short* gB = nullptr;
  unsigned short* lB = Bs + (w * 32) * 32;
  if (!CVTW) gB = Wb + (size_t)(blockIdx.x * 128 + w * 32 + (lane >> 2)) * K
                     + kst + (lane & 3) * 8;
  // CVT mapping: 8 lanes per row (k-offset (tid&7)*4), 4 rows per thread.
  const int crow = tid >> 3;            // 0..31
  const int ck4  = (tid & 7) << 2;      // 0,4,..,28

  f32x4 acc[4][4];
  #pragma unroll
  for (int i = 0; i < 4; ++i)
    #pragma unroll
    for (int j = 0; j < 4; ++j)
      #pragma unroll
      for (int r = 0; r < 4; ++r) acc[i][j][r] = 0.f;

  for (int ks = 0; ks < ksteps; ++ks) {
    if (!CVTA) {
      #pragma unroll
      for (int p = 0; p < NP; ++p) {
        async_copy16(gA + p * 32, lA + p * 4096);
        async_copy16(gA + (size_t)16 * K + p * 32, lA + p * 4096 + 16 * 32);
      }
      gA += BK;
    } else {
      #pragma unroll
      for (int p = 0; p < NP; ++p)
        #pragma unroll
        for (int rr = 0; rr < 4; ++rr) {
          int row128 = crow + 32 * rr;
          const float* asrc = Af + (size_t)((int)blockIdx.y * 128 + row128) * K
                                 + ks * BK + p * 32 + ck4;
          float4 v = *reinterpret_cast<const float4*>(asrc);
          ushort4 o; o.x = f2bf(v.x); o.y = f2bf(v.y); o.z = f2bf(v.z); o.w = f2bf(v.w);
          *reinterpret_cast<ushort4*>(As + p * 4096 + row128 * 32 + ck4) = o;
        }
    }
    if (!CVTW) {
      #pragma unroll
      for (int p = 0; p < NP; ++p) {
        async_copy16(gB + p * 32, lB + p * 4096);
        async_copy16(gB + (size_t)16 * K + p * 32, lB + p * 4096 + 16 * 32);
      }
      gB += BK;
    } else {
      #pragma unroll
      for (int p = 0; p < NP; ++p)
        #pragma unroll
        for (int rr = 0; rr < 4; ++rr) {
          int row128 = crow + 32 * rr;
          int wrow = blockIdx.x * 128 + row128;
          if (wrow >= Dout) wrow = Dout - 1;
          const float* wsrc = Wf + (size_t)wrow * K + kst + ks * BK + p * 32 + ck4;
          float4 v = *reinterpret_cast<const float4*>(wsrc);
          ushort4 o; o.x = f2bf(v.x); o.y = f2bf(v.y); o.z = f2bf(v.z); o.w = f2bf(v.w);
          *reinterpret_cast<ushort4*>(Bs + p * 4096 + row128 * 32 + ck4) = o;
        }
    }
    __syncthreads();
    #pragma unroll
    for (int p = 0; p < NP; ++p) {
      const unsigned short* pa = As + p * 4096 + (64 * (w >> 1) + r16) * 32 + quad * 8;
      const unsigned short* pb = Bs + p * 4096 + (64 * (w & 1) + r16) * 32 + quad * 8;
      short8 af[4], bfv[4];
      #pragma unroll
      for (int i = 0; i < 4; ++i) af[i] = *reinterpret_cast<const short8*>(pa + i * 512);
      #pragma unroll
      for (int j = 0; j < 4; ++j) bfv[j] = *reinterpret_cast<const short8*>(pb + j * 512);
      #pragma unroll
      for (int i = 0; i < 4; ++i)
        #pragma unroll
        for (int j = 0; j < 4; ++j)
          acc[i][j] = __builtin_amdgcn_mfma_f32_16x16x32_bf16(af[i], bfv[j], acc[i][j], 0, 0, 0);
    }
    __syncthreads();
  }

  float* Cf = (float*)Cv;
  unsigned short* Cb = (unsigned short*)Cv;
  if (SPLITK) Cf += (size_t)blockIdx.z * prow * Dout;
  const int colb = blockIdx.x * 128 + 64 * (w & 1) + r16;
  const int rowb = blockIdx.y * 128 + 64 * (w >> 1) + quad * 4;
  #pragma unroll
  for (int j = 0; j < 4; ++j) {
    int col = colb + 16 * j;
    float bv = 0.f;
    if (BIASM == 0) bv = bias[col];
    else if (BIASM == 1) bv = (col & 1) ? 2.0f * bias[col >> 1] : 0.f;
    bool colok = (BIASM != 2) || (col < Dout);
    #pragma unroll
    for (int i = 0; i < 4; ++i) {
      #pragma unroll
      for (int r = 0; r < 4; ++r) {
        int row = rowb + 16 * i + r;
        float v = acc[i][j][r] + bv;
        if (ACT == 1) v = gelu_exact(v);
        if (SHRINK) {
          float o = __shfl_xor(v, 1, 64);
          float mag = sqrtf(v * v + o * o);
          float s = (mag > LAM_) ? (mag - LAM_) / (mag + 1e-8f) : 0.f;
          v *= s;
        }
        if (MULPT) v *= bf2f(ptb[(size_t)row * Dout + col]);
        if (colok) {
          if (OUTBF) Cb[(size_t)row * Dout + col] = f2bf(v);
          else       Cf[(size_t)row * Dout + col] = v;
        }
      }
    }
  }
}

// ---------------------------------------------------------------- norm
__global__ __launch_bounds__(256) void norm_kernel(const float* __restrict__ x,
    float* __restrict__ xn, float* __restrict__ meanb, float* __restrict__ stdb) {
  __shared__ float red[4];
  int bm = blockIdx.x;
  const float* xr = x + (size_t)bm * L_;
  float v0 = xr[threadIdx.x], v1 = xr[threadIdx.x + 256];
  float mu = block_sum256(v0 + v1, red) * (1.0f / L_);
  float d0 = v0 - mu, d1 = v1 - mu;
  float sd = sqrtf(block_sum256(d0 * d0 + d1 * d1, red) * (1.0f / L_));
  float inv = 1.0f / (sd + 1e-5f);
  float* xo = xn + (size_t)bm * L_;
  xo[threadIdx.x] = d0 * inv;
  xo[threadIdx.x + 256] = d1 * inv;
  if (threadIdx.x == 0) { meanb[bm] = mu; stdb[bm] = sd; }
}

// ---------------------------------------------------------------- im2col -> bf16 K=352
__global__ __launch_bounds__(256) void im2col_kernel(const float* __restrict__ xn,
                                                     unsigned short* __restrict__ im) {
  int row = blockIdx.x;
  int b = row / T_, t = row - b * T_;
  const float* xb = xn + (size_t)b * M_ * L_ + t * 8;
  unsigned short* o = im + (size_t)row * KCP_;
  for (int i = threadIdx.x; i < KCP_; i += 256) {
    float v = 0.f;
    if (i < 336) { int m = i >> 4, p = i & 15; v = xb[m * L_ + p]; }
    o[i] = f2bf(v);
  }
}

// ---------------------------------------------------------------- pos-enc + dup into both towers
__global__ __launch_bounds__(256) void add_pe_kernel(const float* __restrict__ g0,
                                                     float* __restrict__ x32) {
  int row = blockIdx.x, d = threadIdx.x;
  int t = row % T_;
  size_t idx = (size_t)row * D_ + d;
  float freq = expf((float)(d & ~1) * (-9.210340371976184f / 256.0f));
  float ang = (float)t * freq;
  float pe = (d & 1) ? cosf(ang) : sinf(ang);
  float h = g0[idx] + pe;
  x32[idx] = h;
  x32[idx + (size_t)NT_ * D_] = h;
}

// ---------------------------------------------------------------- DFT along T (rfft)
__global__ __launch_bounds__(256) void dft_kernel(const float* __restrict__ X,
                                                  unsigned short* __restrict__ Zcat) {
  __shared__ float2 tw[T_ * F_];     // 15.75 KB
  int bt = blockIdx.x, d = threadIdx.x;
  for (int i = threadIdx.x; i < T_ * F_; i += 256) {
    int t = i >> 5, f = i & 31;
    int k = (f * t) % T_;
    float sn, cs;
    sincosf((6.283185307179586f / 63.0f) * (float)k, &sn, &cs);
    tw[i] = make_float2(cs, -sn);
  }
  __syncthreads();
  const float* xb = X + (size_t)bt * T_ * D_ + d;
  float ar[F_], ai[F_];
  #pragma unroll
  for (int f = 0; f < F_; ++f) { ar[f] = 0.f; ai[f] = 0.f; }
  for (int t = 0; t < T_; ++t) {
    float v = xb[(size_t)t * D_];
    const float2* w = &tw[t * F_];
    #pragma unroll
    for (int f = 0; f < F_; ++f) {
      float2 c = w[f];
      ar[f] = fmaf(v, c.x, ar[f]);
      ai[f] = fmaf(v, c.y, ai[f]);
    }
  }
  u32* z = reinterpret_cast<u32*>(Zcat + (size_t)bt * F_ * 512);
  #pragma unroll
  for (int f = 0; f < F_; ++f)
    z[f * 256 + d] = (u32)f2bf(ar[f]) | ((u32)f2bf(ai[f]) << 16);
}

// ---------------------------------------------------------------- irfft(n=63) -> pt bf16 (bf16 packed input)
__global__ __launch_bounds__(256) void irfft_kernel(const unsigned short* __restrict__ Y,
                                                    unsigned short* __restrict__ ptb) {
  __shared__ float2 tw[T_ * 31];     // 15.26 KB
  int bt = blockIdx.x, d = threadIdx.x;
  for (int i = threadIdx.x; i < T_ * 31; i += 256) {
    int t = i / 31, f = i - t * 31 + 1;
    int k = (f * t) % T_;
    float sn, cs;
    sincosf((6.283185307179586f / 63.0f) * (float)k, &sn, &cs);
    tw[i] = make_float2(cs * (2.0f / 63.0f), -sn * (2.0f / 63.0f));
  }
  __syncthreads();
  const unsigned short* yb = Y + (size_t)bt * F_ * 512 + 2 * d;
  float y0 = bf2f(yb[0]) * (1.0f / 63.0f);   // f=0: Re only
  float yr[31], yi[31];
  #pragma unroll
  for (int f = 1; f < F_; ++f) {
    u32 p = *reinterpret_cast<const u32*>(yb + (size_t)f * 512);
    yr[f - 1] = bf2f((unsigned short)(p & 0xffff));
    yi[f - 1] = bf2f((unsigned short)(p >> 16));
  }
  unsigned short* po = ptb + (size_t)bt * T_ * D_ + d;
  for (int t = 0; t < T_; ++t) {
    const float2* w = &tw[t * 31];
    float acc0 = y0, acc1 = 0.f;
    #pragma unroll
    for (int f = 0; f < 31; f += 2) {
      float2 c = w[f];
      acc0 = fmaf(yr[f], c.x, fmaf(yi[f], c.y, acc0));
      if (f + 1 < 31) {
        float2 c1 = w[f + 1];
        acc1 = fmaf(yr[f + 1], c1.x, fmaf(yi[f + 1], c1.y, acc1));
      }
    }
    po[(size_t)t * D_] = f2bf(acc0 + acc1);
  }
}

// ---------------------------------------------------------------- add + layernorm (wave per row)
__global__ __launch_bounds__(256) void ln_kernel(const float* __restrict__ outb,
    float* __restrict__ x, const float* __restrict__ g0, const float* __restrict__ b0,
    const float* __restrict__ g1, const float* __restrict__ b1, int yhalf) {
  int row = blockIdx.x * 4 + (threadIdx.x >> 6);
  int lane = threadIdx.x & 63;
  const float* g = (row >= yhalf) ? g1 : g0;
  const float* b = (row >= yhalf) ? b1 : b0;
  size_t base = (size_t)row * D_ + lane * 4;
  float4 ov = *reinterpret_cast<const float4*>(outb + base);
  float4 xv = *reinterpret_cast<const float4*>(x + base);
  float v0 = ov.x + xv.x, v1 = ov.y + xv.y, v2 = ov.z + xv.z, v3 = ov.w + xv.w;
  float mu = wave_sum(v0 + v1 + v2 + v3) * (1.0f / D_);
  v0 -= mu; v1 -= mu; v2 -= mu; v3 -= mu;
  float var = wave_sum(v0 * v0 + v1 * v1 + v2 * v2 + v3 * v3) * (1.0f / D_);
  float is = rsqrtf(var + 1e-5f);
  float4 gv = *reinterpret_cast<const float4*>(g + lane * 4);
  float4 bv = *reinterpret_cast<const float4*>(b + lane * 4);
  float4 o;
  o.x = v0 * is * gv.x + bv.x;
  o.y = v1 * is * gv.y + bv.y;
  o.z = v2 * is * gv.z + bv.z;
  o.w = v3 * is * gv.w + bv.w;
  *reinterpret_cast<float4*>(x + base) = o;
}

// ---------------------------------------------------------------- gate + blend -> bf16 feat (wave per row)
__global__ __launch_bounds__(256) void gate_feat_kernel(const float* __restrict__ x32,
    const float* __restrict__ gw, const float* __restrict__ gb,
    unsigned short* __restrict__ featbf) {
  int row = blockIdx.x * 4 + (threadIdx.x >> 6);
  int lane = threadIdx.x & 63;
  size_t base = (size_t)row * D_ + lane * 4;
  float4 tv = *reinterpret_cast<const float4*>(x32 + base);
  float4 sv = *reinterpret_cast<const float4*>(x32 + base + (size_t)NT_ * D_);
  float4 gv = *reinterpret_cast<const float4*>(gw + lane * 4);
  float dot = wave_sum(tv.x * gv.x + tv.y * gv.y + tv.z * gv.z + tv.w * gv.w) + gb[0];
  float gate = 1.0f / (1.0f + expf(-dot));
  ushort4 o;
  o.x = f2bf(gate * tv.x + (1.0f - gate) * sv.x);
  o.y = f2bf(gate * tv.y + (1.0f - gate) * sv.y);
  o.z = f2bf(gate * tv.z + (1.0f - gate) * sv.z);
  o.w = f2bf(gate * tv.w + (1.0f - gate) * sv.w);
  *reinterpret_cast<ushort4*>(featbf + base) = o;
}

// ---------------------------------------------------------------- split-K reduce + bias + rescale
__global__ __launch_bounds__(256) void final_kernel(const float* __restrict__ part,
    const float* __restrict__ pb, const float* __restrict__ stdb,
    const float* __restrict__ meanb, float* __restrict__ y) {
  int i = blockIdx.x * 256 + threadIdx.x;         // 516096
  float acc = 0.f;
  #pragma unroll
  for (int z = 0; z < PZ_; ++z) acc += part[(size_t)z * 516096 + i];
  int b = i / 2016;
  int col = i - b * 2016;
  int m = col / H_;
  float sc = stdb[b * M_ + m] + 1e-5f;
  y[i] = (acc + pb[col]) * sc + meanb[b * M_ + m];
}

// ---------------------------------------------------------------- launch
extern "C" void kernel_launch(void* const* d_in, const int* in_sizes, int n_in,
                              void* d_out, int out_size, void* d_ws, size_t ws_size,
                              hipStream_t stream) {
  const float* x      = (const float*)d_in[0];
  const float* conv_w = (const float*)d_in[1];
  const float* conv_b = (const float*)d_in[2];
  const float* tP[16];
  const float* sP[16];
  for (int i = 0; i < 16; ++i) tP[i] = (const float*)d_in[3 + i];
  for (int i = 0; i < 16; ++i) sP[i] = (const float*)d_in[19 + i];
  const float* gate_w = (const float*)d_in[35];
  const float* gate_b = (const float*)d_in[36];
  const float* proj_w = (const float*)d_in[37];
  const float* proj_b = (const float*)d_in[38];
  float* out = (float*)d_out;

  // ---- workspace (floats): total 27,646,480 f = 110.6 MB
  float* ws    = (float*)d_ws;
  float* x32   = ws;                               // 8,257,536 (2 towers x NT x D)
  unsigned short* wb = (unsigned short*)(x32 + 8257536);  // 5,201,920 shorts
  float* meanb = x32 + 8257536 + 2600960;          // 5,376
  float* stdb  = meanb + 5376;                     // 5,376
  float* R1    = stdb + 5376 + 16;                 // 8,388,608
  float* R2    = R1 + 8388608;                     // 8,388,608

  unsigned short* im2colB = (unsigned short*)R1;             // pre-loop
  unsigned short* Zcat    = (unsigned short*)R1;             // dft -> H1
  unsigned short* Ycat1   = (unsigned short*)(R1 + 4194304); // H1 -> H2
  unsigned short* ptb     = (unsigned short*)(R1 + 4194304); // irfft -> Gp
  unsigned short* gp      = (unsigned short*)R1;             // Gp -> Tw
  unsigned short* featbf  = (unsigned short*)R1;             // post-loop

  float* xn     = R2;                              // pre-loop
  float* g0buf  = R2;                              // conv out (pre-loop)
  unsigned short* Ycat2b = (unsigned short*)R2;    // H2 -> irfft (bf16 packed)
  unsigned short* hidB = (unsigned short*)R2;      // Ge -> Gp
  float* outb   = R2;                              // Tw -> ln
  float* part   = R2;                              // proj partials (PZ_ x 516096 = 7.22M f)

  unsigned short* convW = wb;                      // 256*352
  unsigned short* sets  = wb + 90112;              // 6 * (Gew 131072 + Gpw 131072 + Tw 65536)
  unsigned short* catW  = wb + 90112 + 1966080;    // 12 * 262144

  // ---- weight prep
  CvtArgs ca; int blk0 = 0, ne = 0;
  auto add_ent = [&](const float* s, unsigned short* d, int rows, int scol, int dcol) {
    ca.e[ne].src = s; ca.e[ne].dst = d; ca.e[ne].rows = rows;
    ca.e[ne].scol = scol; ca.e[ne].dcol = dcol; ca.e[ne].blk0 = blk0;
    blk0 += (rows * dcol + 255) / 256; ++ne;
  };
  add_ent(conv_w, convW, 256, 336, 352);
  for (int tw = 0; tw < 2; ++tw) {
    const float** Pp = tw ? (const float**)sP : (const float**)tP;
    for (int l = 0; l < 3; ++l) {
      unsigned short* sb = sets + (size_t)(tw * 3 + l) * 327680;
      add_ent(Pp[2] + (size_t)l * 131072, sb,          512, 256, 256);  // Gew
      add_ent(Pp[4] + (size_t)l * 131072, sb + 131072, 256, 512, 512);  // Gpw
      add_ent(Pp[0] + (size_t)l * 65536,  sb + 262144, 256, 256, 256);  // Tw
    }
  }
  ca.nent = ne;
  wprep_kernel<<<blk0, 256, 0, stream>>>(ca);

  CatArgs cat;
  for (int tw = 0; tw < 2; ++tw) {
    const float** Pp = tw ? (const float**)sP : (const float**)tP;
    for (int l = 0; l < 3; ++l) {
      int e0 = (tw * 3 + l) * 2;
      cat.wr[e0]     = Pp[6]  + (size_t)l * 65536;   // H1Wr
      cat.wi[e0]     = Pp[7]  + (size_t)l * 65536;   // H1Wi
      cat.wr[e0 + 1] = Pp[10] + (size_t)l * 65536;   // H2Wr
      cat.wi[e0 + 1] = Pp[11] + (size_t)l * 65536;   // H2Wi
    }
  }
  wcat_kernel<<<12 * 1024, 256, 0, stream>>>(cat, catW);

  // ---- stem
  norm_kernel<<<B_ * M_, 256, 0, stream>>>(x, xn, meanb, stdb);
  im2col_kernel<<<NT_, 256, 0, stream>>>(xn, im2colB);
  mm_kernel<0, 0, 0, 11, 0, 0, 0, 0, 0, 32><<<dim3(2, 126), 256, 0, stream>>>(
      im2colB, convW, convW, nullptr, conv_b, conv_b, nullptr, g0buf,
      KCP_, 256, 0, 1 << 30, 0);
  add_pe_kernel<<<NT_, 256, 0, stream>>>(g0buf, x32);

  // ---- layers (both towers batched; freq branch first, then MLP with x pt fuse)
  for (int l = 0; l < 3; ++l) {
    unsigned short* st0 = sets + (size_t)l * 327680;
    unsigned short* st1 = sets + (size_t)(3 + l) * 327680;
    unsigned short* c1t0 = catW + (size_t)((0 + l) * 2) * 262144;
    unsigned short* c2t0 = c1t0 + 262144;
    unsigned short* c1t1 = catW + (size_t)((3 + l) * 2) * 262144;
    unsigned short* c2t1 = c1t1 + 262144;

    dft_kernel<<<2 * B_, 256, 0, stream>>>(x32, Zcat);
    mm_kernel<0, 1, 1, 8, 0, 0, 1, 0, 0, 64><<<dim3(4, 128), 256, 0, stream>>>(
        Zcat, c1t0, c1t1, nullptr, tP[9] + (size_t)l * D_, sP[9] + (size_t)l * D_,
        nullptr, Ycat1, 512, 512, 0, 64, 0);
    mm_kernel<0, 1, 1, 8, 0, 0, 0, 0, 0, 64><<<dim3(4, 128), 256, 0, stream>>>(
        Ycat1, c2t0, c2t1, nullptr, tP[13] + (size_t)l * D_, sP[13] + (size_t)l * D_,
        nullptr, Ycat2b, 512, 512, 0, 64, 0);
    irfft_kernel<<<2 * B_, 256, 0, stream>>>(Ycat2b, ptb);
    mm_kernel<1, 1, 0, 4, 1, 0, 0, 0, 0, 64><<<dim3(4, 252), 256, 0, stream>>>(
        x32, st0, st1, nullptr, tP[3] + (size_t)l * HID_, sP[3] + (size_t)l * HID_,
        nullptr, hidB, 256, 512, 0, 126, 0);
    mm_kernel<0, 1, 0, 8, 0, 0, 0, 1, 0, 64><<<dim3(2, 252), 256, 0, stream>>>(
        hidB, st0 + 131072, st1 + 131072, nullptr,
        tP[5] + (size_t)l * D_, sP[5] + (size_t)l * D_, ptb, gp, 512, 256, 0, 126, 0);
    mm_kernel<0, 0, 0, 4, 0, 0, 0, 0, 0, 64><<<dim3(2, 252), 256, 0, stream>>>(
        gp, st0 + 262144, st1 + 262144, nullptr,
        tP[1] + (size_t)l * D_, sP[1] + (size_t)l * D_, nullptr, outb, 256, 256, 0, 126, 0);
    ln_kernel<<<2 * NT_ / 4, 256, 0, stream>>>(outb, x32,
        tP[14] + (size_t)l * D_, tP[15] + (size_t)l * D_,
        sP[14] + (size_t)l * D_, sP[15] + (size_t)l * D_, NT_);
  }

  // ---- head
  gate_feat_kernel<<<NT_ / 4, 256, 0, stream>>>(x32, gate_w, gate_b, featbf);
  mm_kernel<0, 0, 2, 0, 0, 1, 0, 0, 1, 32><<<dim3(16, 2, PZ_), 256, 0, stream>>>(
      featbf, nullptr, nullptr, proj_w, nullptr, nullptr, nullptr, part,
      NT_, 2016, 504 / PZ_, 1 << 30, 256);
  final_kernel<<<2016, 256, 0, stream>>>(part, proj_b, stdb, meanb, out);
}

// Round 6
// 1009.507 us; speedup vs baseline: 4.0687x; 1.0128x over previous
//
#include <hip/hip_runtime.h>
#include <cstddef>
#include <cstdint>

#define B_    256
#define M_    21
#define L_    512
#define D_    256
#define T_    63
#define F_    32
#define NT_   16128   // B_*T_
#define HID_  512
#define KCP_  352     // M_*P_=336 padded to 32
#define H_    96
#define LAM_  0.01f
#define PZ_   16      // proj split-K z-blocks (each 32 k32-steps, last clamps to 24)

typedef __attribute__((ext_vector_type(8))) short short8;
typedef __attribute__((ext_vector_type(4))) float f32x4;
typedef unsigned int u32;
typedef const u32 __attribute__((address_space(1)))* gas1_t;
typedef u32 __attribute__((address_space(3)))* las3_t;

__device__ __forceinline__ void async_copy16(const void* g, void* l) {
  __builtin_amdgcn_global_load_lds((gas1_t)g, (las3_t)(uintptr_t)l, 16, 0, 0);
}
__device__ __forceinline__ unsigned short f2bf(float x) {   // RNE
  unsigned u = __float_as_uint(x);
  return (unsigned short)((u + 0x7FFF + ((u >> 16) & 1)) >> 16);
}
__device__ __forceinline__ float bf2f(unsigned short u) {
  return __uint_as_float(((unsigned)u) << 16);
}
__device__ __forceinline__ float gelu_exact(float v) {
  return 0.5f * v * (1.0f + erff(v * 0.70710678118654752f));
}
__device__ __forceinline__ float block_sum256(float v, float* red4) {
  #pragma unroll
  for (int off = 32; off > 0; off >>= 1) v += __shfl_down(v, off, 64);
  if ((threadIdx.x & 63) == 0) red4[threadIdx.x >> 6] = v;
  __syncthreads();
  float r = red4[0] + red4[1] + red4[2] + red4[3];
  __syncthreads();
  return r;
}
__device__ __forceinline__ float wave_sum(float v) {
  #pragma unroll
  for (int off = 1; off < 64; off <<= 1) v += __shfl_xor(v, off, 64);
  return v;
}

// ---------------------------------------------------------------- weight prep
struct CvtEnt { const float* src; unsigned short* dst; int rows, scol, dcol, blk0; };
struct CvtArgs { CvtEnt e[19]; int nent; };
__global__ __launch_bounds__(256) void wprep_kernel(CvtArgs a) {
  int blk = blockIdx.x, e = 0;
  while (e + 1 < a.nent && a.e[e + 1].blk0 <= blk) ++e;
  CvtEnt en = a.e[e];
  int idx = (blk - en.blk0) * 256 + threadIdx.x;
  int total = en.rows * en.dcol;
  if (idx >= total) return;
  int r = idx / en.dcol, c = idx - r * en.dcol;
  float v = (c < en.scol) ? en.src[(size_t)r * en.scol + c] : 0.f;
  en.dst[idx] = f2bf(v);
}

// interleaved cat weight: row 2c+p, col 2d+q
struct CatArgs { const float* wr[12]; const float* wi[12]; };
__global__ __launch_bounds__(256) void wcat_kernel(CatArgs a, unsigned short* dst) {
  int e = blockIdx.x >> 10;
  int idx = ((blockIdx.x & 1023) << 8) + threadIdx.x;
  int r = idx >> 9, c = idx & 511;
  int cp = r >> 1, p = r & 1, d = c >> 1, q = c & 1;
  const float* wr = a.wr[e];
  const float* wi = a.wi[e];
  float v;
  if (p == 0) v = (q == 0) ? wr[cp * 256 + d] : -wi[cp * 256 + d];
  else        v = (q == 0) ? wi[cp * 256 + d] :  wr[cp * 256 + d];
  dst[(size_t)e * 262144 + idx] = f2bf(v);
}

// ---------------------------------------------------------------- MFMA GEMM
// C = A @ W^T (+bias). Block tile (32*RT) x 128, 4 waves (2x2), each wave
// RT x 4 of 16x16x32-bf16 MFMA. BK = 32 or 64, LDS as [BK/32][rows][32] panels.
// BIASM: 0 normal, 1 interleaved clin (odd col: 2*bi[col>>1]), 2 none+col guard.
// CVTA/CVTW: stage from fp32 with depth-1 register prefetch (loads for step
// ks+1 issued after barrier1, overlapped with MFMA of step ks).
template <int ACT, int OUTBF, int BIASM, int KSTEPS, int CVTA, int CVTW,
          int SHRINK, int MULPT, int SPLITK, int BK, int RT>
__global__ __launch_bounds__(256) void mm_kernel(
    const void* __restrict__ Av,
    const unsigned short* __restrict__ W0, const unsigned short* __restrict__ W1,
    const float* __restrict__ Wf,
    const float* __restrict__ b0, const float* __restrict__ b1,
    const unsigned short* __restrict__ ptb,
    void* __restrict__ Cv,
    const int K, const int Dout, const int ksteps_rt, const int yhalf,
    const int prow, const int totk) {
  constexpr int NP = BK / 32;
  constexpr int RWS = 32 * RT;
  __shared__ __align__(16) unsigned short As[NP * RWS * 32];
  __shared__ __align__(16) unsigned short Bs[NP * 128 * 32];
  const int tid = threadIdx.x, w = tid >> 6, lane = tid & 63;
  const int quad = lane >> 4, r16 = lane & 15;
  int nks = KSTEPS ? KSTEPS : ksteps_rt;
  const int ksbeg = SPLITK ? (int)blockIdx.z * nks : 0;
  if (SPLITK) { int rem = totk - ksbeg; if (nks > rem) nks = rem; }
  const int kst = ksbeg * BK;
  const int tower = ((int)blockIdx.y >= yhalf) ? 1 : 0;
  const unsigned short* Wb = tower ? W1 : W0;
  const float* bias = tower ? b1 : b0;

  const unsigned short* Ab = (const unsigned short*)Av;
  const float* Af = (const float*)Av;
  const unsigned short* gA = nullptr;
  unsigned short* lA = As + (w * 8 * RT) * 32;
  if (!CVTA) gA = Ab + (size_t)((int)blockIdx.y * RWS + w * 8 * RT + (lane >> 2)) * K
                     + kst + (lane & 3) * 8;
  const unsigned short* gB = nullptr;
  unsigned short* lB = Bs + (w * 32) * 32;
  if (!CVTW) gB = Wb + (size_t)((int)blockIdx.x * 128 + w * 32 + (lane >> 2)) * K
                     + kst + (lane & 3) * 8;
  // CVT mapping: 8 lanes per row (128B contiguous), rows crow+32*rr.
  const int crow = tid >> 3;            // 0..31
  const int ck4  = (tid & 7) << 2;      // 0,4,..,28

  float4 areg[NP][RT];
  float4 wreg[NP][4];
  auto loadA = [&](int ksi) {
    #pragma unroll
    for (int p = 0; p < NP; ++p)
      #pragma unroll
      for (int rr = 0; rr < RT; ++rr)
        areg[p][rr] = *reinterpret_cast<const float4*>(
            Af + (size_t)((int)blockIdx.y * RWS + crow + 32 * rr) * K
               + kst + ksi * BK + p * 32 + ck4);
  };
  auto loadW = [&](int ksi) {
    #pragma unroll
    for (int p = 0; p < NP; ++p)
      #pragma unroll
      for (int rr = 0; rr < 4; ++rr) {
        int wrow = (int)blockIdx.x * 128 + crow + 32 * rr;
        if (wrow >= Dout) wrow = Dout - 1;
        wreg[p][rr] = *reinterpret_cast<const float4*>(
            Wf + (size_t)wrow * K + kst + ksi * BK + p * 32 + ck4);
      }
  };
  if (CVTA) loadA(0);
  if (CVTW) loadW(0);

  f32x4 acc[RT][4];
  #pragma unroll
  for (int i = 0; i < RT; ++i)
    #pragma unroll
    for (int j = 0; j < 4; ++j)
      #pragma unroll
      for (int r = 0; r < 4; ++r) acc[i][j][r] = 0.f;

  for (int ks = 0; ks < nks; ++ks) {
    if (!CVTA) {
      #pragma unroll
      for (int p = 0; p < NP; ++p)
        #pragma unroll
        for (int c = 0; c < RT / 2; ++c)
          async_copy16(gA + (size_t)(c * 16) * K + p * 32,
                       lA + p * (RWS * 32) + c * 16 * 32);
      gA += BK;
    } else {
      #pragma unroll
      for (int p = 0; p < NP; ++p)
        #pragma unroll
        for (int rr = 0; rr < RT; ++rr) {
          float4 v = areg[p][rr];
          ushort4 o; o.x = f2bf(v.x); o.y = f2bf(v.y); o.z = f2bf(v.z); o.w = f2bf(v.w);
          *reinterpret_cast<ushort4*>(As + p * (RWS * 32) + (crow + 32 * rr) * 32 + ck4) = o;
        }
    }
    if (!CVTW) {
      #pragma unroll
      for (int p = 0; p < NP; ++p) {
        async_copy16(gB + p * 32, lB + p * 4096);
        async_copy16(gB + (size_t)16 * K + p * 32, lB + p * 4096 + 16 * 32);
      }
      gB += BK;
    } else {
      #pragma unroll
      for (int p = 0; p < NP; ++p)
        #pragma unroll
        for (int rr = 0; rr < 4; ++rr) {
          float4 v = wreg[p][rr];
          ushort4 o; o.x = f2bf(v.x); o.y = f2bf(v.y); o.z = f2bf(v.z); o.w = f2bf(v.w);
          *reinterpret_cast<ushort4*>(Bs + p * 4096 + (crow + 32 * rr) * 32 + ck4) = o;
        }
    }
    __syncthreads();
    if (CVTA && ks + 1 < nks) loadA(ks + 1);
    if (CVTW && ks + 1 < nks) loadW(ks + 1);
    #pragma unroll
    for (int p = 0; p < NP; ++p) {
      const unsigned short* pa = As + p * (RWS * 32) + ((w >> 1) * 16 * RT + r16) * 32 + quad * 8;
      const unsigned short* pb = Bs + p * 4096 + (64 * (w & 1) + r16) * 32 + quad * 8;
      short8 af[RT], bfv[4];
      #pragma unroll
      for (int i = 0; i < RT; ++i) af[i] = *reinterpret_cast<const short8*>(pa + i * 512);
      #pragma unroll
      for (int j = 0; j < 4; ++j) bfv[j] = *reinterpret_cast<const short8*>(pb + j * 512);
      #pragma unroll
      for (int i = 0; i < RT; ++i)
        #pragma unroll
        for (int j = 0; j < 4; ++j)
          acc[i][j] = __builtin_amdgcn_mfma_f32_16x16x32_bf16(af[i], bfv[j], acc[i][j], 0, 0, 0);
    }
    __syncthreads();
  }

  float* Cf = (float*)Cv;
  unsigned short* Cb = (unsigned short*)Cv;
  if (SPLITK) Cf += (size_t)blockIdx.z * prow * Dout;
  const int colb = (int)blockIdx.x * 128 + 64 * (w & 1) + r16;
  const int rowb = (int)blockIdx.y * RWS + 16 * RT * (w >> 1) + quad * 4;
  #pragma unroll
  for (int j = 0; j < 4; ++j) {
    int col = colb + 16 * j;
    float bv = 0.f;
    if (BIASM == 0) bv = bias[col];
    else if (BIASM == 1) bv = (col & 1) ? 2.0f * bias[col >> 1] : 0.f;
    bool colok = (BIASM != 2) || (col < Dout);
    #pragma unroll
    for (int i = 0; i < RT; ++i) {
      #pragma unroll
      for (int r = 0; r < 4; ++r) {
        int row = rowb + 16 * i + r;
        float v = acc[i][j][r] + bv;
        if (ACT == 1) v = gelu_exact(v);
        if (SHRINK) {
          float o = __shfl_xor(v, 1, 64);
          float mag = sqrtf(v * v + o * o);
          float s = (mag > LAM_) ? (mag - LAM_) / (mag + 1e-8f) : 0.f;
          v *= s;
        }
        if (MULPT) v *= bf2f(ptb[(size_t)row * Dout + col]);
        if (colok) {
          if (OUTBF) Cb[(size_t)row * Dout + col] = f2bf(v);
          else       Cf[(size_t)row * Dout + col] = v;
        }
      }
    }
  }
}

// ---------------------------------------------------------------- norm
__global__ __launch_bounds__(256) void norm_kernel(const float* __restrict__ x,
    float* __restrict__ xn, float* __restrict__ meanb, float* __restrict__ stdb) {
  __shared__ float red[4];
  int bm = blockIdx.x;
  const float* xr = x + (size_t)bm * L_;
  float v0 = xr[threadIdx.x], v1 = xr[threadIdx.x + 256];
  float mu = block_sum256(v0 + v1, red) * (1.0f / L_);
  float d0 = v0 - mu, d1 = v1 - mu;
  float sd = sqrtf(block_sum256(d0 * d0 + d1 * d1, red) * (1.0f / L_));
  float inv = 1.0f / (sd + 1e-5f);
  float* xo = xn + (size_t)bm * L_;
  xo[threadIdx.x] = d0 * inv;
  xo[threadIdx.x + 256] = d1 * inv;
  if (threadIdx.x == 0) { meanb[bm] = mu; stdb[bm] = sd; }
}

// ---------------------------------------------------------------- im2col -> bf16 K=352
__global__ __launch_bounds__(256) void im2col_kernel(const float* __restrict__ xn,
                                                     unsigned short* __restrict__ im) {
  int row = blockIdx.x;
  int b = row / T_, t = row - b * T_;
  const float* xb = xn + (size_t)b * M_ * L_ + t * 8;
  unsigned short* o = im + (size_t)row * KCP_;
  for (int i = threadIdx.x; i < KCP_; i += 256) {
    float v = 0.f;
    if (i < 336) { int m = i >> 4, p = i & 15; v = xb[m * L_ + p]; }
    o[i] = f2bf(v);
  }
}

// ---------------------------------------------------------------- pos-enc + dup into both towers
__global__ __launch_bounds__(256) void add_pe_kernel(const float* __restrict__ g0,
                                                     float* __restrict__ x32) {
  int row = blockIdx.x, d = threadIdx.x;
  int t = row % T_;
  size_t idx = (size_t)row * D_ + d;
  float freq = expf((float)(d & ~1) * (-9.210340371976184f / 256.0f));
  float ang = (float)t * freq;
  float pe = (d & 1) ? cosf(ang) : sinf(ang);
  float h = g0[idx] + pe;
  x32[idx] = h;
  x32[idx + (size_t)NT_ * D_] = h;
}

// ---------------------------------------------------------------- DFT along T (rfft)
__global__ __launch_bounds__(256) void dft_kernel(const float* __restrict__ X,
                                                  unsigned short* __restrict__ Zcat) {
  __shared__ float2 tw[T_ * F_];     // 15.75 KB
  int bt = blockIdx.x, d = threadIdx.x;
  for (int i = threadIdx.x; i < T_ * F_; i += 256) {
    int t = i >> 5, f = i & 31;
    int k = (f * t) % T_;
    float sn, cs;
    sincosf((6.283185307179586f / 63.0f) * (float)k, &sn, &cs);
    tw[i] = make_float2(cs, -sn);
  }
  __syncthreads();
  const float* xb = X + (size_t)bt * T_ * D_ + d;
  float ar[F_], ai[F_];
  #pragma unroll
  for (int f = 0; f < F_; ++f) { ar[f] = 0.f; ai[f] = 0.f; }
  for (int t = 0; t < T_; ++t) {
    float v = xb[(size_t)t * D_];
    const float2* w = &tw[t * F_];
    #pragma unroll
    for (int f = 0; f < F_; ++f) {
      float2 c = w[f];
      ar[f] = fmaf(v, c.x, ar[f]);
      ai[f] = fmaf(v, c.y, ai[f]);
    }
  }
  u32* z = reinterpret_cast<u32*>(Zcat + (size_t)bt * F_ * 512);
  #pragma unroll
  for (int f = 0; f < F_; ++f)
    z[f * 256 + d] = (u32)f2bf(ar[f]) | ((u32)f2bf(ai[f]) << 16);
}

// ---------------------------------------------------------------- irfft(n=63) -> pt bf16 (bf16 packed input)
__global__ __launch_bounds__(256) void irfft_kernel(const unsigned short* __restrict__ Y,
                                                    unsigned short* __restrict__ ptb) {
  __shared__ float2 tw[T_ * 31];     // 15.26 KB
  int bt = blockIdx.x, d = threadIdx.x;
  for (int i = threadIdx.x; i < T_ * 31; i += 256) {
    int t = i / 31, f = i - t * 31 + 1;
    int k = (f * t) % T_;
    float sn, cs;
    sincosf((6.283185307179586f / 63.0f) * (float)k, &sn, &cs);
    tw[i] = make_float2(cs * (2.0f / 63.0f), -sn * (2.0f / 63.0f));
  }
  __syncthreads();
  const unsigned short* yb = Y + (size_t)bt * F_ * 512 + 2 * d;
  float y0 = bf2f(yb[0]) * (1.0f / 63.0f);   // f=0: Re only
  float yr[31], yi[31];
  #pragma unroll
  for (int f = 1; f < F_; ++f) {
    u32 p = *reinterpret_cast<const u32*>(yb + (size_t)f * 512);
    yr[f - 1] = bf2f((unsigned short)(p & 0xffff));
    yi[f - 1] = bf2f((unsigned short)(p >> 16));
  }
  unsigned short* po = ptb + (size_t)bt * T_ * D_ + d;
  for (int t = 0; t < T_; ++t) {
    const float2* w = &tw[t * 31];
    float acc0 = y0, acc1 = 0.f;
    #pragma unroll
    for (int f = 0; f < 31; f += 2) {
      float2 c = w[f];
      acc0 = fmaf(yr[f], c.x, fmaf(yi[f], c.y, acc0));
      if (f + 1 < 31) {
        float2 c1 = w[f + 1];
        acc1 = fmaf(yr[f + 1], c1.x, fmaf(yi[f + 1], c1.y, acc1));
      }
    }
    po[(size_t)t * D_] = f2bf(acc0 + acc1);
  }
}

// ---------------------------------------------------------------- add + layernorm (wave per row)
__global__ __launch_bounds__(256) void ln_kernel(const float* __restrict__ outb,
    float* __restrict__ x, const float* __restrict__ g0, const float* __restrict__ b0,
    const float* __restrict__ g1, const float* __restrict__ b1, int yhalf) {
  int row = blockIdx.x * 4 + (threadIdx.x >> 6);
  int lane = threadIdx.x & 63;
  const float* g = (row >= yhalf) ? g1 : g0;
  const float* b = (row >= yhalf) ? b1 : b0;
  size_t base = (size_t)row * D_ + lane * 4;
  float4 ov = *reinterpret_cast<const float4*>(outb + base);
  float4 xv = *reinterpret_cast<const float4*>(x + base);
  float v0 = ov.x + xv.x, v1 = ov.y + xv.y, v2 = ov.z + xv.z, v3 = ov.w + xv.w;
  float mu = wave_sum(v0 + v1 + v2 + v3) * (1.0f / D_);
  v0 -= mu; v1 -= mu; v2 -= mu; v3 -= mu;
  float var = wave_sum(v0 * v0 + v1 * v1 + v2 * v2 + v3 * v3) * (1.0f / D_);
  float is = rsqrtf(var + 1e-5f);
  float4 gv = *reinterpret_cast<const float4*>(g + lane * 4);
  float4 bv = *reinterpret_cast<const float4*>(b + lane * 4);
  float4 o;
  o.x = v0 * is * gv.x + bv.x;
  o.y = v1 * is * gv.y + bv.y;
  o.z = v2 * is * gv.z + bv.z;
  o.w = v3 * is * gv.w + bv.w;
  *reinterpret_cast<float4*>(x + base) = o;
}

// ---------------------------------------------------------------- gate + blend -> bf16 feat (wave per row)
__global__ __launch_bounds__(256) void gate_feat_kernel(const float* __restrict__ x32,
    const float* __restrict__ gw, const float* __restrict__ gb,
    unsigned short* __restrict__ featbf) {
  int row = blockIdx.x * 4 + (threadIdx.x >> 6);
  int lane = threadIdx.x & 63;
  size_t base = (size_t)row * D_ + lane * 4;
  float4 tv = *reinterpret_cast<const float4*>(x32 + base);
  float4 sv = *reinterpret_cast<const float4*>(x32 + base + (size_t)NT_ * D_);
  float4 gv = *reinterpret_cast<const float4*>(gw + lane * 4);
  float dot = wave_sum(tv.x * gv.x + tv.y * gv.y + tv.z * gv.z + tv.w * gv.w) + gb[0];
  float gate = 1.0f / (1.0f + expf(-dot));
  ushort4 o;
  o.x = f2bf(gate * tv.x + (1.0f - gate) * sv.x);
  o.y = f2bf(gate * tv.y + (1.0f - gate) * sv.y);
  o.z = f2bf(gate * tv.z + (1.0f - gate) * sv.z);
  o.w = f2bf(gate * tv.w + (1.0f - gate) * sv.w);
  *reinterpret_cast<ushort4*>(featbf + base) = o;
}

// ---------------------------------------------------------------- split-K reduce + bias + rescale
__global__ __launch_bounds__(256) void final_kernel(const float* __restrict__ part,
    const float* __restrict__ pb, const float* __restrict__ stdb,
    const float* __restrict__ meanb, float* __restrict__ y) {
  int i = blockIdx.x * 256 + threadIdx.x;         // 516096
  float acc = 0.f;
  #pragma unroll
  for (int z = 0; z < PZ_; ++z) acc += part[(size_t)z * 516096 + i];
  int b = i / 2016;
  int col = i - b * 2016;
  int m = col / H_;
  float sc = stdb[b * M_ + m] + 1e-5f;
  y[i] = (acc + pb[col]) * sc + meanb[b * M_ + m];
}

// ---------------------------------------------------------------- launch
extern "C" void kernel_launch(void* const* d_in, const int* in_sizes, int n_in,
                              void* d_out, int out_size, void* d_ws, size_t ws_size,
                              hipStream_t stream) {
  const float* x      = (const float*)d_in[0];
  const float* conv_w = (const float*)d_in[1];
  const float* conv_b = (const float*)d_in[2];
  const float* tP[16];
  const float* sP[16];
  for (int i = 0; i < 16; ++i) tP[i] = (const float*)d_in[3 + i];
  for (int i = 0; i < 16; ++i) sP[i] = (const float*)d_in[19 + i];
  const float* gate_w = (const float*)d_in[35];
  const float* gate_b = (const float*)d_in[36];
  const float* proj_w = (const float*)d_in[37];
  const float* proj_b = (const float*)d_in[38];
  float* out = (float*)d_out;

  // ---- workspace (floats): total 27,646,480 f = 110.6 MB
  float* ws    = (float*)d_ws;
  float* x32   = ws;                               // 8,257,536 (2 towers x NT x D)
  unsigned short* wb = (unsigned short*)(x32 + 8257536);  // 5,201,920 shorts
  float* meanb = x32 + 8257536 + 2600960;          // 5,376
  float* stdb  = meanb + 5376;                     // 5,376
  float* R1    = stdb + 5376 + 16;                 // 8,388,608
  float* R2    = R1 + 8388608;                     // 8,388,608

  unsigned short* im2colB = (unsigned short*)R1;             // pre-loop
  unsigned short* Zcat    = (unsigned short*)R1;             // dft -> H1
  unsigned short* Ycat1   = (unsigned short*)(R1 + 4194304); // H1 -> H2
  unsigned short* ptb     = (unsigned short*)(R1 + 4194304); // irfft -> Gp
  unsigned short* gp      = (unsigned short*)R1;             // Gp -> Tw
  unsigned short* featbf  = (unsigned short*)R1;             // post-loop

  float* xn     = R2;                              // pre-loop
  float* g0buf  = R2;                              // conv out (pre-loop)
  unsigned short* Ycat2b = (unsigned short*)R2;    // H2 -> irfft (bf16 packed)
  unsigned short* hidB = (unsigned short*)R2;      // Ge -> Gp
  float* outb   = R2;                              // Tw -> ln
  float* part   = R2;                              // proj partials (16 x 516096 = 8.26M f)

  unsigned short* convW = wb;                      // 256*352
  unsigned short* sets  = wb + 90112;              // 6 * (Gew 131072 + Gpw 131072 + Tw 65536)
  unsigned short* catW  = wb + 90112 + 1966080;    // 12 * 262144

  // ---- weight prep
  CvtArgs ca; int blk0 = 0, ne = 0;
  auto add_ent = [&](const float* s, unsigned short* d, int rows, int scol, int dcol) {
    ca.e[ne].src = s; ca.e[ne].dst = d; ca.e[ne].rows = rows;
    ca.e[ne].scol = scol; ca.e[ne].dcol = dcol; ca.e[ne].blk0 = blk0;
    blk0 += (rows * dcol + 255) / 256; ++ne;
  };
  add_ent(conv_w, convW, 256, 336, 352);
  for (int tw = 0; tw < 2; ++tw) {
    const float** Pp = tw ? (const float**)sP : (const float**)tP;
    for (int l = 0; l < 3; ++l) {
      unsigned short* sb = sets + (size_t)(tw * 3 + l) * 327680;
      add_ent(Pp[2] + (size_t)l * 131072, sb,          512, 256, 256);  // Gew
      add_ent(Pp[4] + (size_t)l * 131072, sb + 131072, 256, 512, 512);  // Gpw
      add_ent(Pp[0] + (size_t)l * 65536,  sb + 262144, 256, 256, 256);  // Tw
    }
  }
  ca.nent = ne;
  wprep_kernel<<<blk0, 256, 0, stream>>>(ca);

  CatArgs cat;
  for (int tw = 0; tw < 2; ++tw) {
    const float** Pp = tw ? (const float**)sP : (const float**)tP;
    for (int l = 0; l < 3; ++l) {
      int e0 = (tw * 3 + l) * 2;
      cat.wr[e0]     = Pp[6]  + (size_t)l * 65536;   // H1Wr
      cat.wi[e0]     = Pp[7]  + (size_t)l * 65536;   // H1Wi
      cat.wr[e0 + 1] = Pp[10] + (size_t)l * 65536;   // H2Wr
      cat.wi[e0 + 1] = Pp[11] + (size_t)l * 65536;   // H2Wi
    }
  }
  wcat_kernel<<<12 * 1024, 256, 0, stream>>>(cat, catW);

  // ---- stem
  norm_kernel<<<B_ * M_, 256, 0, stream>>>(x, xn, meanb, stdb);
  im2col_kernel<<<NT_, 256, 0, stream>>>(xn, im2colB);
  mm_kernel<0, 0, 0, 11, 0, 0, 0, 0, 0, 32, 2><<<dim3(2, 252), 256, 0, stream>>>(
      im2colB, convW, convW, nullptr, conv_b, conv_b, nullptr, g0buf,
      KCP_, 256, 0, 1 << 30, 0, 0);
  add_pe_kernel<<<NT_, 256, 0, stream>>>(g0buf, x32);

  // ---- layers (both towers batched; freq branch first, then MLP with x pt fuse)
  for (int l = 0; l < 3; ++l) {
    unsigned short* st0 = sets + (size_t)l * 327680;
    unsigned short* st1 = sets + (size_t)(3 + l) * 327680;
    unsigned short* c1t0 = catW + (size_t)((0 + l) * 2) * 262144;
    unsigned short* c2t0 = c1t0 + 262144;
    unsigned short* c1t1 = catW + (size_t)((3 + l) * 2) * 262144;
    unsigned short* c2t1 = c1t1 + 262144;

    dft_kernel<<<2 * B_, 256, 0, stream>>>(x32, Zcat);
    mm_kernel<0, 1, 1, 8, 0, 0, 1, 0, 0, 64, 2><<<dim3(4, 256), 256, 0, stream>>>(
        Zcat, c1t0, c1t1, nullptr, tP[9] + (size_t)l * D_, sP[9] + (size_t)l * D_,
        nullptr, Ycat1, 512, 512, 0, 128, 0, 0);
    mm_kernel<0, 1, 1, 8, 0, 0, 0, 0, 0, 64, 2><<<dim3(4, 256), 256, 0, stream>>>(
        Ycat1, c2t0, c2t1, nullptr, tP[13] + (size_t)l * D_, sP[13] + (size_t)l * D_,
        nullptr, Ycat2b, 512, 512, 0, 128, 0, 0);
    irfft_kernel<<<2 * B_, 256, 0, stream>>>(Ycat2b, ptb);
    mm_kernel<1, 1, 0, 4, 1, 0, 0, 0, 0, 64, 2><<<dim3(4, 504), 256, 0, stream>>>(
        x32, st0, st1, nullptr, tP[3] + (size_t)l * HID_, sP[3] + (size_t)l * HID_,
        nullptr, hidB, 256, 512, 0, 252, 0, 0);
    mm_kernel<0, 1, 0, 8, 0, 0, 0, 1, 0, 64, 2><<<dim3(2, 504), 256, 0, stream>>>(
        hidB, st0 + 131072, st1 + 131072, nullptr,
        tP[5] + (size_t)l * D_, sP[5] + (size_t)l * D_, ptb, gp, 512, 256, 0, 252, 0, 0);
    mm_kernel<0, 0, 0, 4, 0, 0, 0, 0, 0, 64, 2><<<dim3(2, 504), 256, 0, stream>>>(
        gp, st0 + 262144, st1 + 262144, nullptr,
        tP[1] + (size_t)l * D_, sP[1] + (size_t)l * D_, nullptr, outb, 256, 256, 0, 252, 0, 0);
    ln_kernel<<<2 * NT_ / 4, 256, 0, stream>>>(outb, x32,
        tP[14] + (size_t)l * D_, tP[15] + (size_t)l * D_,
        sP[14] + (size_t)l * D_, sP[15] + (size_t)l * D_, NT_);
  }

  // ---- head
  gate_feat_kernel<<<NT_ / 4, 256, 0, stream>>>(x32, gate_w, gate_b, featbf);
  mm_kernel<0, 0, 2, 0, 0, 1, 0, 0, 1, 32, 2><<<dim3(16, 4, PZ_), 256, 0, stream>>>(
      featbf, nullptr, nullptr, proj_w, nullptr, nullptr, nullptr, part,
      NT_, 2016, 32, 1 << 30, 256, 504);
  final_kernel<<<2016, 256, 0, stream>>>(part, proj_b, stdb, meanb, out);
}